// Round 7
// baseline (296.317 us; speedup 1.0000x reference)
//
#include <hip/hip_runtime.h>
#include <hip/hip_fp16.h>

typedef _Float16 f16x8 __attribute__((ext_vector_type(8)));
typedef float    f32x4 __attribute__((ext_vector_type(4)));

#define MFMA16(a,b,c) __builtin_amdgcn_mfma_f32_16x16x32_f16(a,b,c,0,0,0)

__device__ __forceinline__ void gload_lds16(const void* g, void* l) {
  __builtin_amdgcn_global_load_lds(
      (const __attribute__((address_space(1))) void*)g,
      (__attribute__((address_space(3))) void*)l, 16, 0, 0);
}

// ---------------- fp32 -> fp16 conversion ----------------
__global__ void cvt_f32_f16(const float* __restrict__ src,
                            _Float16* __restrict__ dst, int n8) {
  int i = blockIdx.x * blockDim.x + threadIdx.x;
  int stride = gridDim.x * blockDim.x;
  for (; i < n8; i += stride) {
    const float4* s = (const float4*)src + 2 * (size_t)i;
    float4 a = s[0], b = s[1];
    f16x8 o;
    o[0]=(_Float16)a.x; o[1]=(_Float16)a.y; o[2]=(_Float16)a.z; o[3]=(_Float16)a.w;
    o[4]=(_Float16)b.x; o[5]=(_Float16)b.y; o[6]=(_Float16)b.z; o[7]=(_Float16)b.w;
    ((f16x8*)dst)[i] = o;
  }
}

// ---------------- cache_V f32 [32][4096][128] -> V^T f16 [32][128][4096] ----------------
__global__ __launch_bounds__(256) void cvt_transpose_v(const float* __restrict__ src,
                                                       _Float16* __restrict__ dst) {
  __shared__ _Float16 t[64][72];
  const int b = blockIdx.x;        // 32 h x 64 l-tiles x 2 d-tiles
  const int h = b >> 7, rest = b & 127;
  const int lt = rest >> 1, dt = rest & 1;
  const int l0 = lt * 64, d0 = dt * 64;
  const int tid = threadIdx.x;
  const int r = tid >> 4, c4 = (tid & 15) * 4;
#pragma unroll
  for (int i = 0; i < 4; i++) {
    int l = r + i * 16;
    float4 v = *(const float4*)&src[((size_t)h * 4096 + l0 + l) * 128 + d0 + c4];
    t[c4 + 0][l] = (_Float16)v.x;
    t[c4 + 1][l] = (_Float16)v.y;
    t[c4 + 2][l] = (_Float16)v.z;
    t[c4 + 3][l] = (_Float16)v.w;
  }
  __syncthreads();
  const int d = tid >> 2, lc = (tid & 3) * 16;
#pragma unroll
  for (int i = 0; i < 2; i++) {
    f16x8 o = *(const f16x8*)&t[d][lc + i * 8];
    *(f16x8*)&dst[((size_t)h * 128 + d0 + d) * 4096 + l0 + lc + i * 8] = o;
  }
}

// ---------------- fused QKV GEMM: 128x128 tile, wave 64x64, BK=64 ----------------
// C[512,12288] = X16 @ [Wq;Wk;Wv]^T. Grid 384 = 8 XCD x (12 nt x 4 mt); single-buffer
// 2-barrier loop (m97 structure); LDS fragment reads = 0.5 b128/MFMA.
__global__ __launch_bounds__(256) void qkv_gemm(
    const _Float16* __restrict__ X,
    const float* __restrict__ Wq,
    const float* __restrict__ Wk,
    const float* __restrict__ Wv,
    _Float16* __restrict__ Q16,
    _Float16* __restrict__ Kc,
    _Float16* __restrict__ Vt16,
    const int* __restrict__ Pp)
{
  __shared__ __align__(16) _Float16 As[128 * 64];   // 16KB, 128B rows, XOR-swizzled
  __shared__ __align__(16) _Float16 Bs[128 * 64];   // 16KB, 128B rows, XOR-swizzled
  const int bid = blockIdx.x;                 // 384 = 8 xcd * 48
  const int xcd = bid & 7, s = bid >> 3;      // s 0..47
  const int nt = xcd * 12 + (s >> 2);         // 12 consecutive n-panels per XCD
  const int mt = s & 3;                       // 4 m-blocks of same panel co-XCD
  const int m0 = mt * 128, n0 = nt * 128;
  const int tid = threadIdx.x, wave = tid >> 6, lane = tid & 63;
  const int g = lane >> 4, c = lane & 15;
  const int wr = wave >> 1, wc = wave & 1;    // wave tile = 64m x 64n
  const float* Wp = (n0 < 4096) ? Wq : ((n0 < 8192) ? Wk : Wv);
  const int n0l = n0 & 4095;
  // A staging: 16 chunks x 8 rows x 128B; lane -> row ar, byte col acs
  const int ar  = lane >> 3;
  const int acs = (lane & 7) * 16;
  // B staging: 2 threads/row; thread covers 32 consecutive f32 (128B)
  const int brow = tid >> 1;                  // 0..127
  const int bhalf = tid & 1;                  // 0/1 -> f32 col 0/32
  const float* wsrc = Wp + (size_t)(n0l + brow) * 4096 + bhalf * 32;
  const int bsw = (brow & 7) << 4;

  float4 b0, b1, b2, b3, b4, b5, b6, b7;      // 32 f32 in flight
  auto loadB = [&](int k0) {
    const float* ns = wsrc + k0;
    b0 = *(const float4*)(ns);      b1 = *(const float4*)(ns + 4);
    b2 = *(const float4*)(ns + 8);  b3 = *(const float4*)(ns + 12);
    b4 = *(const float4*)(ns + 16); b5 = *(const float4*)(ns + 20);
    b6 = *(const float4*)(ns + 24); b7 = *(const float4*)(ns + 28);
  };
  auto writeB = [&]() {
    f16x8 h0, h1, h2, h3;
    h0[0]=(_Float16)b0.x; h0[1]=(_Float16)b0.y; h0[2]=(_Float16)b0.z; h0[3]=(_Float16)b0.w;
    h0[4]=(_Float16)b1.x; h0[5]=(_Float16)b1.y; h0[6]=(_Float16)b1.z; h0[7]=(_Float16)b1.w;
    h1[0]=(_Float16)b2.x; h1[1]=(_Float16)b2.y; h1[2]=(_Float16)b2.z; h1[3]=(_Float16)b2.w;
    h1[4]=(_Float16)b3.x; h1[5]=(_Float16)b3.y; h1[6]=(_Float16)b3.z; h1[7]=(_Float16)b3.w;
    h2[0]=(_Float16)b4.x; h2[1]=(_Float16)b4.y; h2[2]=(_Float16)b4.z; h2[3]=(_Float16)b4.w;
    h2[4]=(_Float16)b5.x; h2[5]=(_Float16)b5.y; h2[6]=(_Float16)b5.z; h2[7]=(_Float16)b5.w;
    h3[0]=(_Float16)b6.x; h3[1]=(_Float16)b6.y; h3[2]=(_Float16)b6.z; h3[3]=(_Float16)b6.w;
    h3[4]=(_Float16)b7.x; h3[5]=(_Float16)b7.y; h3[6]=(_Float16)b7.z; h3[7]=(_Float16)b7.w;
    char* rb = (char*)Bs + brow * 128;
    const int cb = bhalf * 64;
    *(f16x8*)(rb + ((cb)      ^ bsw)) = h0;
    *(f16x8*)(rb + ((cb + 16) ^ bsw)) = h1;
    *(f16x8*)(rb + ((cb + 32) ^ bsw)) = h2;
    *(f16x8*)(rb + ((cb + 48) ^ bsw)) = h3;
  };

  f32x4 acc[4][4] = {};
  loadB(0);
  for (int k0 = 0; k0 < 4096; k0 += 64) {
    __syncthreads();                          // waves done reading prev tile
    // ---- A -> LDS (async, swizzled global source, linear dest) ----
#pragma unroll
    for (int p = 0; p < 4; p++) {
      int chunk = wave * 4 + p;
      int row = chunk * 8 + ar;
      gload_lds16((const char*)(X + (size_t)(m0 + row) * 4096 + k0) + (acs ^ ((row & 7) << 4)),
                  (char*)As + chunk * 1024);
    }
    // ---- B: cvt prefetched regs -> swizzled LDS; prefetch next tile ----
    writeB();
    if (k0 + 64 < 4096) loadB(k0 + 64);       // latency covered by MFMA phase
    __syncthreads();                          // staged data visible
    // ---- fragments (matching XOR) + MFMA ----
    f16x8 af[2][4], bf[2][4];
#pragma unroll
    for (int mi = 0; mi < 4; mi++) {
      int row = wr * 64 + mi * 16 + c;
      int sw = (row & 7) << 4;
#pragma unroll
      for (int kc = 0; kc < 2; kc++)
        af[kc][mi] = *(const f16x8*)((const char*)As + row * 128 + ((kc * 64 + g * 16) ^ sw));
    }
#pragma unroll
    for (int ni = 0; ni < 4; ni++) {
      int row = wc * 64 + ni * 16 + c;
      int sw = (row & 7) << 4;
#pragma unroll
      for (int kc = 0; kc < 2; kc++)
        bf[kc][ni] = *(const f16x8*)((const char*)Bs + row * 128 + ((kc * 64 + g * 16) ^ sw));
    }
#pragma unroll
    for (int kc = 0; kc < 2; kc++)
#pragma unroll
      for (int mi = 0; mi < 4; mi++)
#pragma unroll
        for (int ni = 0; ni < 4; ni++)
          acc[mi][ni] = MFMA16(af[kc][mi], bf[kc][ni], acc[mi][ni]);
  }
  // ---- epilogue: cvt f16 + scatter (block covers full d-range of one head) ----
  const int p = Pp[0];
  const int wsel = n0 >> 12;
  const int h = (n0 & 4095) >> 7;
#pragma unroll
  for (int mi = 0; mi < 4; mi++) {
#pragma unroll
    for (int ni = 0; ni < 4; ni++) {
#pragma unroll
      for (int j = 0; j < 4; j++) {
        int m = m0 + wr * 64 + mi * 16 + 4 * g + j;
        int d = wc * 64 + ni * 16 + c;
        _Float16 hv = (_Float16)acc[mi][ni][j];
        if (wsel == 0)      Q16[(size_t)(h * 512 + m) * 128 + d] = hv;
        else if (wsel == 1) Kc[(size_t)(h * 4096 + p + m) * 128 + d] = hv;
        else                Vt16[((size_t)h * 128 + d) * 4096 + p + m] = hv;
      }
    }
  }
}

// ---------------- flash attention: LDS-staged K/V, 8 waves x 32 q-rows ----------------
// grid = 256 (1/CU): 4 lsplits x 32 heads x 2 m-tiles(256 rows). BL=64.
__global__ __launch_bounds__(512, 2) void attn_part(
    const _Float16* __restrict__ Q16,
    const _Float16* __restrict__ Kc,     // [32][4096][128]
    const _Float16* __restrict__ Vt,     // [32][128][4096]
    float* __restrict__ Opart,           // [4][32][512][128]
    float* __restrict__ Mpart,           // [4][32][512]
    float* __restrict__ Lpart)           // [4][32][512]
{
  __shared__ __align__(16) _Float16 Ks[64 * 128];
  __shared__ __align__(16) _Float16 Vs[128 * 64];
  __shared__ __align__(16) _Float16 Pl[8][32][68];
  const int bid = blockIdx.x;
  const int xcd = bid & 7, s = bid >> 3;
  const int group = xcd * 16 + (s >> 1);
  const int mt = s & 1;
  const int ls = group >> 5, h = group & 31;
  const int m0 = mt * 256;
  const int tid = threadIdx.x, wave = tid >> 6, lane = tid & 63;
  const int g = lane >> 4, c = lane & 15;
  const int mw = m0 + wave * 32;
  const _Float16* Kh  = Kc + (size_t)h * 4096 * 128;
  const _Float16* Vth = Vt + (size_t)h * 128 * 4096;
  f16x8 qf[2][4];
#pragma unroll
  for (int mi = 0; mi < 2; mi++)
#pragma unroll
    for (int kc = 0; kc < 4; kc++)
      qf[mi][kc] = *(const f16x8*)&Q16[(size_t)(h * 512 + mw + mi * 16 + c) * 128 + kc * 32 + g * 8];
  f32x4 o[2][8] = {};
  float mrow[2][4], lrow[2][4];
#pragma unroll
  for (int mi = 0; mi < 2; mi++)
#pragma unroll
    for (int j = 0; j < 4; j++) { mrow[mi][j] = -3e38f; lrow[mi][j] = 0.f; }
  const int klr = lane >> 4, klb = (lane & 15) * 16;
  const int vlr = lane >> 3, vlb = (lane & 7) * 16;

  const int l_begin = ls * 1024;
  for (int l0 = l_begin; l0 < l_begin + 1024; l0 += 64) {
    __syncthreads();
#pragma unroll
    for (int p = 0; p < 2; p++) {
      int chunk = p * 8 + wave;
      int kr = chunk * 4 + klr;
      gload_lds16((const char*)Kh + (size_t)(l0 + kr) * 256 + (klb ^ ((kr & 7) << 4)),
                  (char*)Ks + chunk * 1024);
      int vd = chunk * 8 + vlr;
      gload_lds16((const char*)Vth + (size_t)vd * 8192 + (size_t)l0 * 2 + (vlb ^ ((vd & 7) << 4)),
                  (char*)Vs + chunk * 1024);
    }
    __syncthreads();
    f32x4 sc[2][4] = {};
#pragma unroll
    for (int ni = 0; ni < 4; ni++) {
      int kr = ni * 16 + c;
      f16x8 kf[4];
#pragma unroll
      for (int kc = 0; kc < 4; kc++)
        kf[kc] = *(const f16x8*)((const char*)Ks + kr * 256 + ((kc * 64 + g * 16) ^ ((kr & 7) << 4)));
#pragma unroll
      for (int mi = 0; mi < 2; mi++)
#pragma unroll
        for (int kc = 0; kc < 4; kc++)
          sc[mi][ni] = MFMA16(qf[mi][kc], kf[kc], sc[mi][ni]);
    }
#pragma unroll
    for (int mi = 0; mi < 2; mi++) {
      float scale[4];
#pragma unroll
      for (int j = 0; j < 4; j++) {
        float tm = sc[mi][0][j];
#pragma unroll
        for (int ni = 1; ni < 4; ni++) tm = fmaxf(tm, sc[mi][ni][j]);
        tm = fmaxf(tm, __shfl_xor(tm, 1, 64));
        tm = fmaxf(tm, __shfl_xor(tm, 2, 64));
        tm = fmaxf(tm, __shfl_xor(tm, 4, 64));
        tm = fmaxf(tm, __shfl_xor(tm, 8, 64));
        float mn = fmaxf(mrow[mi][j], tm);
        scale[j] = __expf(mrow[mi][j] - mn);
        mrow[mi][j] = mn;
      }
      float rs[4] = {0.f, 0.f, 0.f, 0.f};
#pragma unroll
      for (int ni = 0; ni < 4; ni++) {
#pragma unroll
        for (int j = 0; j < 4; j++) {
          float pv = __expf(sc[mi][ni][j] - mrow[mi][j]);
          sc[mi][ni][j] = pv;
          rs[j] += pv;
        }
      }
#pragma unroll
      for (int j = 0; j < 4; j++) {
        rs[j] += __shfl_xor(rs[j], 1, 64);
        rs[j] += __shfl_xor(rs[j], 2, 64);
        rs[j] += __shfl_xor(rs[j], 4, 64);
        rs[j] += __shfl_xor(rs[j], 8, 64);
        lrow[mi][j] = lrow[mi][j] * scale[j] + rs[j];
      }
#pragma unroll
      for (int dn = 0; dn < 8; dn++)
#pragma unroll
        for (int j = 0; j < 4; j++) o[mi][dn][j] *= scale[j];
#pragma unroll
      for (int ni = 0; ni < 4; ni++)
#pragma unroll
        for (int j = 0; j < 4; j++)
          Pl[wave][mi * 16 + 4 * g + j][ni * 16 + c] = (_Float16)sc[mi][ni][j];
    }
    f16x8 pa[2][2];
#pragma unroll
    for (int mi = 0; mi < 2; mi++)
#pragma unroll
      for (int kc = 0; kc < 2; kc++)
        pa[mi][kc] = *(const f16x8*)&Pl[wave][mi * 16 + c][kc * 32 + g * 8];
#pragma unroll
    for (int dn = 0; dn < 8; dn++) {
      int vr = dn * 16 + c;
#pragma unroll
      for (int kc = 0; kc < 2; kc++) {
        f16x8 vb = *(const f16x8*)((const char*)Vs + vr * 128 + ((kc * 64 + g * 16) ^ ((vr & 7) << 4)));
#pragma unroll
        for (int mi = 0; mi < 2; mi++)
          o[mi][dn] = MFMA16(pa[mi][kc], vb, o[mi][dn]);
      }
    }
  }
  const size_t pbase = ((size_t)(ls * 32 + h) * 512);
#pragma unroll
  for (int mi = 0; mi < 2; mi++) {
#pragma unroll
    for (int dn = 0; dn < 8; dn++) {
#pragma unroll
      for (int j = 0; j < 4; j++) {
        int m = mw + mi * 16 + 4 * g + j;
        Opart[(pbase + m) * 128 + dn * 16 + c] = o[mi][dn][j];
      }
    }
  }
  if (c == 0) {
#pragma unroll
    for (int mi = 0; mi < 2; mi++)
#pragma unroll
      for (int j = 0; j < 4; j++) {
        int m = mw + mi * 16 + 4 * g + j;
        Mpart[pbase + m] = mrow[mi][j];
        Lpart[pbase + m] = lrow[mi][j];
      }
  }
}

// ---------------- combine 4 split-L partials ----------------
__global__ __launch_bounds__(256) void attn_combine(
    const float* __restrict__ Opart,
    const float* __restrict__ Mpart,
    const float* __restrict__ Lpart,
    float* __restrict__ out)
{
  int idx = blockIdx.x * 256 + threadIdx.x;
  int row = idx >> 5;
  int d4  = idx & 31;
  int h = row >> 9, m = row & 511;
  float Ms[4];
  float mx = -3e38f;
#pragma unroll
  for (int s = 0; s < 4; s++) {
    Ms[s] = Mpart[(size_t)(s * 32 + h) * 512 + m];
    mx = fmaxf(mx, Ms[s]);
  }
  float lsum = 0.f;
  float4 acc = make_float4(0.f, 0.f, 0.f, 0.f);
#pragma unroll
  for (int s = 0; s < 4; s++) {
    float w = __expf(Ms[s] - mx);
    lsum += w * Lpart[(size_t)(s * 32 + h) * 512 + m];
    float4 ov = ((const float4*)(Opart + ((size_t)(s * 32 + h) * 512 + m) * 128))[d4];
    acc.x += w * ov.x; acc.y += w * ov.y; acc.z += w * ov.z; acc.w += w * ov.w;
  }
  float inv = 1.f / lsum;
  float4 r = make_float4(acc.x * inv, acc.y * inv, acc.z * inv, acc.w * inv);
  *(float4*)&out[(size_t)m * 4096 + h * 128 + d4 * 4] = r;
}

extern "C" void kernel_launch(void* const* d_in, const int* in_sizes, int n_in,
                              void* d_out, int out_size, void* d_ws, size_t ws_size,
                              hipStream_t stream) {
  const float* X  = (const float*)d_in[0];
  const float* Wq = (const float*)d_in[1];
  const float* Wk = (const float*)d_in[2];
  const float* Wv = (const float*)d_in[3];
  const float* cK = (const float*)d_in[4];
  const float* cV = (const float*)d_in[5];
  const int*   Pp = (const int*)d_in[6];
  float* out = (float*)d_out;

  char* ws = (char*)d_ws;
  _Float16* X16  = (_Float16*)(ws);                           // 4 MB
  _Float16* Q16  = (_Float16*)(ws + ((size_t)100 << 20));     // 4 MB
  _Float16* K16  = (_Float16*)(ws + ((size_t)104 << 20));     // 32 MB [32][4096][128]
  _Float16* V16t = (_Float16*)(ws + ((size_t)136 << 20));     // 32 MB [32][128][4096]
  float* Opart = (float*)(ws + ((size_t)4  << 20));           // 32 MB
  float* Mpart = (float*)(ws + ((size_t)36 << 20));
  float* Lpart = (float*)(ws + ((size_t)37 << 20));

  const int NTH = 256;
  auto cvtl = [&](const float* s, _Float16* d, size_t n) {
    int n8 = (int)(n / 8);
    int grid = (n8 + NTH - 1) / NTH;
    if (grid > 2048) grid = 2048;
    cvt_f32_f16<<<dim3(grid), dim3(NTH), 0, stream>>>(s, d, n8);
  };
  cvtl(X,  X16, (size_t)512 * 4096);
  cvtl(cK, K16, (size_t)32 * 4096 * 128);
  cvt_transpose_v<<<dim3(4096), dim3(NTH), 0, stream>>>(cV, V16t);

  qkv_gemm<<<dim3(384), dim3(256), 0, stream>>>(X16, Wq, Wk, Wv, Q16, K16, V16t, Pp);
  attn_part<<<dim3(256), dim3(512), 0, stream>>>(Q16, K16, V16t, Opart, Mpart, Lpart);
  attn_combine<<<dim3(2048), dim3(256), 0, stream>>>(Opart, Mpart, Lpart, out);
}

// Round 8
// 267.256 us; speedup vs baseline: 1.1087x; 1.1087x over previous
//
#include <hip/hip_runtime.h>
#include <hip/hip_fp16.h>

typedef _Float16 f16x8 __attribute__((ext_vector_type(8)));
typedef float    f32x4 __attribute__((ext_vector_type(4)));

#define MFMA16(a,b,c) __builtin_amdgcn_mfma_f32_16x16x32_f16(a,b,c,0,0,0)

__device__ __forceinline__ void gload_lds16(const void* g, void* l) {
  __builtin_amdgcn_global_load_lds(
      (const __attribute__((address_space(1))) void*)g,
      (__attribute__((address_space(3))) void*)l, 16, 0, 0);
}

// ---------------- fp32 -> fp16 conversion ----------------
__global__ void cvt_f32_f16(const float* __restrict__ src,
                            _Float16* __restrict__ dst, int n8) {
  int i = blockIdx.x * blockDim.x + threadIdx.x;
  int stride = gridDim.x * blockDim.x;
  for (; i < n8; i += stride) {
    const float4* s = (const float4*)src + 2 * (size_t)i;
    float4 a = s[0], b = s[1];
    f16x8 o;
    o[0]=(_Float16)a.x; o[1]=(_Float16)a.y; o[2]=(_Float16)a.z; o[3]=(_Float16)a.w;
    o[4]=(_Float16)b.x; o[5]=(_Float16)b.y; o[6]=(_Float16)b.z; o[7]=(_Float16)b.w;
    ((f16x8*)dst)[i] = o;
  }
}

// ---------------- cache_V f32 [32][4096][128] -> V^T f16 [32][128][4096] ----------------
__global__ __launch_bounds__(256) void cvt_transpose_v(const float* __restrict__ src,
                                                       _Float16* __restrict__ dst) {
  __shared__ _Float16 t[64][72];
  const int b = blockIdx.x;        // 32 h x 64 l-tiles x 2 d-tiles
  const int h = b >> 7, rest = b & 127;
  const int lt = rest >> 1, dt = rest & 1;
  const int l0 = lt * 64, d0 = dt * 64;
  const int tid = threadIdx.x;
  const int r = tid >> 4, c4 = (tid & 15) * 4;
#pragma unroll
  for (int i = 0; i < 4; i++) {
    int l = r + i * 16;
    float4 v = *(const float4*)&src[((size_t)h * 4096 + l0 + l) * 128 + d0 + c4];
    t[c4 + 0][l] = (_Float16)v.x;
    t[c4 + 1][l] = (_Float16)v.y;
    t[c4 + 2][l] = (_Float16)v.z;
    t[c4 + 3][l] = (_Float16)v.w;
  }
  __syncthreads();
  const int d = tid >> 2, lc = (tid & 3) * 16;
#pragma unroll
  for (int i = 0; i < 2; i++) {
    f16x8 o = *(const f16x8*)&t[d][lc + i * 8];
    *(f16x8*)&dst[((size_t)h * 128 + d0 + d) * 4096 + l0 + lc + i * 8] = o;
  }
}

// ---------------- fused QKV GEMM: 128x128 tile, split-K=2, f32 partials ----------------
// Grid 768 = 8 XCD x (12 nt x 2 ks x 4 mt): 3 blocks/CU co-resident; each block
// covers K range [ks*2048, ks*2048+2048) in 32 BK=64 steps (m97-class 2-barrier loop).
// Partials: Cqk[k][m][8192] f32 (Q,K cols), Cv[k][h][d][m] f32 (V, d-major).
__global__ __launch_bounds__(256) void qkv_gemm(
    const _Float16* __restrict__ X,
    const float* __restrict__ Wq,
    const float* __restrict__ Wk,
    const float* __restrict__ Wv,
    float* __restrict__ Cqk,            // [2][512][8192]
    float* __restrict__ Cv)             // [2][32][128][512]
{
  __shared__ __align__(16) _Float16 As[128 * 64];   // 16KB, 128B rows, XOR-swizzled
  __shared__ __align__(16) _Float16 Bs[128 * 64];   // 16KB, 128B rows, XOR-swizzled
  const int bid = blockIdx.x;                 // 768 = 8 xcd * 96
  const int xcd = bid & 7, s = bid >> 3;      // s 0..95
  const int nt = xcd * 12 + (s >> 3);         // 12 consecutive n-panels per XCD
  const int ks = (s >> 2) & 1;                // k-split half
  const int mt = s & 3;                       // 4 m-blocks of same (nt,ks) co-XCD (W reuse)
  const int m0 = mt * 128, n0 = nt * 128;
  const int kbase = ks * 2048, kend = kbase + 2048;
  const int tid = threadIdx.x, wave = tid >> 6, lane = tid & 63;
  const int g = lane >> 4, c = lane & 15;
  const int wr = wave >> 1, wc = wave & 1;    // wave tile = 64m x 64n
  const float* Wp = (n0 < 4096) ? Wq : ((n0 < 8192) ? Wk : Wv);
  const int n0l = n0 & 4095;
  // A staging: 16 chunks x 8 rows x 128B; lane -> row ar, byte col acs
  const int ar  = lane >> 3;
  const int acs = (lane & 7) * 16;
  // B staging: 2 threads/row; thread covers 32 consecutive f32 (128B)
  const int brow = tid >> 1;                  // 0..127
  const int bhalf = tid & 1;                  // 0/1 -> f32 col 0/32
  const float* wsrc = Wp + (size_t)(n0l + brow) * 4096 + bhalf * 32;
  const int bsw = (brow & 7) << 4;

  float4 b0, b1, b2, b3, b4, b5, b6, b7;      // 32 f32 in flight
  auto loadB = [&](int k0) {
    const float* ns = wsrc + k0;
    b0 = *(const float4*)(ns);      b1 = *(const float4*)(ns + 4);
    b2 = *(const float4*)(ns + 8);  b3 = *(const float4*)(ns + 12);
    b4 = *(const float4*)(ns + 16); b5 = *(const float4*)(ns + 20);
    b6 = *(const float4*)(ns + 24); b7 = *(const float4*)(ns + 28);
  };
  auto writeB = [&]() {
    f16x8 h0, h1, h2, h3;
    h0[0]=(_Float16)b0.x; h0[1]=(_Float16)b0.y; h0[2]=(_Float16)b0.z; h0[3]=(_Float16)b0.w;
    h0[4]=(_Float16)b1.x; h0[5]=(_Float16)b1.y; h0[6]=(_Float16)b1.z; h0[7]=(_Float16)b1.w;
    h1[0]=(_Float16)b2.x; h1[1]=(_Float16)b2.y; h1[2]=(_Float16)b2.z; h1[3]=(_Float16)b2.w;
    h1[4]=(_Float16)b3.x; h1[5]=(_Float16)b3.y; h1[6]=(_Float16)b3.z; h1[7]=(_Float16)b3.w;
    h2[0]=(_Float16)b4.x; h2[1]=(_Float16)b4.y; h2[2]=(_Float16)b4.z; h2[3]=(_Float16)b4.w;
    h2[4]=(_Float16)b5.x; h2[5]=(_Float16)b5.y; h2[6]=(_Float16)b5.z; h2[7]=(_Float16)b5.w;
    h3[0]=(_Float16)b6.x; h3[1]=(_Float16)b6.y; h3[2]=(_Float16)b6.z; h3[3]=(_Float16)b6.w;
    h3[4]=(_Float16)b7.x; h3[5]=(_Float16)b7.y; h3[6]=(_Float16)b7.z; h3[7]=(_Float16)b7.w;
    char* rb = (char*)Bs + brow * 128;
    const int cb = bhalf * 64;
    *(f16x8*)(rb + ((cb)      ^ bsw)) = h0;
    *(f16x8*)(rb + ((cb + 16) ^ bsw)) = h1;
    *(f16x8*)(rb + ((cb + 32) ^ bsw)) = h2;
    *(f16x8*)(rb + ((cb + 48) ^ bsw)) = h3;
  };

  f32x4 acc[4][4] = {};
  loadB(kbase);
  for (int k0 = kbase; k0 < kend; k0 += 64) {
    __syncthreads();                          // waves done reading prev tile
#pragma unroll
    for (int p = 0; p < 4; p++) {
      int chunk = wave * 4 + p;
      int row = chunk * 8 + ar;
      gload_lds16((const char*)(X + (size_t)(m0 + row) * 4096 + k0) + (acs ^ ((row & 7) << 4)),
                  (char*)As + chunk * 1024);
    }
    writeB();
    if (k0 + 64 < kend) loadB(k0 + 64);       // latency covered by MFMA phase
    __syncthreads();                          // staged data visible
    f16x8 af[2][4], bf[2][4];
#pragma unroll
    for (int mi = 0; mi < 4; mi++) {
      int row = wr * 64 + mi * 16 + c;
      int sw = (row & 7) << 4;
#pragma unroll
      for (int kc = 0; kc < 2; kc++)
        af[kc][mi] = *(const f16x8*)((const char*)As + row * 128 + ((kc * 64 + g * 16) ^ sw));
    }
#pragma unroll
    for (int ni = 0; ni < 4; ni++) {
      int row = wc * 64 + ni * 16 + c;
      int sw = (row & 7) << 4;
#pragma unroll
      for (int kc = 0; kc < 2; kc++)
        bf[kc][ni] = *(const f16x8*)((const char*)Bs + row * 128 + ((kc * 64 + g * 16) ^ sw));
    }
#pragma unroll
    for (int kc = 0; kc < 2; kc++)
#pragma unroll
      for (int mi = 0; mi < 4; mi++)
#pragma unroll
        for (int ni = 0; ni < 4; ni++)
          acc[mi][ni] = MFMA16(af[kc][mi], bf[kc][ni], acc[mi][ni]);
  }
  // ---- epilogue: f32 partials ----
  const int wsel = n0 >> 12;
  const int h = (n0 & 4095) >> 7;
  if (wsel < 2) {
    float* Cq = Cqk + (size_t)ks * 512 * 8192;
    const int ncol0 = (n0 & 4095) + (wsel ? 4096 : 0);
#pragma unroll
    for (int mi = 0; mi < 4; mi++)
#pragma unroll
      for (int ni = 0; ni < 4; ni++)
#pragma unroll
        for (int j = 0; j < 4; j++) {
          int m = m0 + wr * 64 + mi * 16 + 4 * g + j;
          int d = wc * 64 + ni * 16 + c;
          Cq[(size_t)m * 8192 + ncol0 + d] = acc[mi][ni][j];
        }
  } else {
    float* Cvp = Cv + (size_t)ks * 32 * 128 * 512;
#pragma unroll
    for (int mi = 0; mi < 4; mi++)
#pragma unroll
      for (int ni = 0; ni < 4; ni++) {
        int mb = m0 + wr * 64 + mi * 16 + 4 * g;
        int d = wc * 64 + ni * 16 + c;
        *(f32x4*)&Cvp[((size_t)(h * 128 + d)) * 512 + mb] = acc[mi][ni];  // 16B contiguous
      }
  }
}

// ---------------- reduce split-K partials -> f16 Q/K/V^T ----------------
// blocks [0,4096): QK part; [4096,6144): V part.
__global__ __launch_bounds__(256) void qkv_reduce(
    const float* __restrict__ Cqk,      // [2][512][8192]
    const float* __restrict__ Cv,       // [2][32][128][512]
    _Float16* __restrict__ Q16,         // [32][512][128]
    _Float16* __restrict__ Kc,          // [32][4096][128]
    _Float16* __restrict__ Vt16,        // [32][128][4096]
    const int* __restrict__ Pp)
{
  const int p = Pp[0];
  const int b = blockIdx.x;
  if (b < 4096) {
    int idx = b * 256 + threadIdx.x;        // 1,048,576 threads: [m][8192/4]
    int m = idx >> 11, n4 = (idx & 2047) * 4;
    const float* s0 = Cqk + (size_t)m * 8192 + n4;
    const float* s1 = s0 + (size_t)512 * 8192;
    float4 a = *(const float4*)s0, bb = *(const float4*)s1;
    _Float16 r0 = (_Float16)(a.x + bb.x), r1 = (_Float16)(a.y + bb.y);
    _Float16 r2 = (_Float16)(a.z + bb.z), r3 = (_Float16)(a.w + bb.w);
    _Float16* dst;
    if (n4 < 4096) {
      int h = n4 >> 7, d = n4 & 127;
      dst = Q16 + (size_t)(h * 512 + m) * 128 + d;
    } else {
      int nk = n4 - 4096;
      int h = nk >> 7, d = nk & 127;
      dst = Kc + (size_t)(h * 4096 + p + m) * 128 + d;
    }
    dst[0] = r0; dst[1] = r1; dst[2] = r2; dst[3] = r3;
  } else {
    int idx = (b - 4096) * 256 + threadIdx.x;   // 524,288 threads: [h*128+d][512/4]
    int row = idx >> 7, m4 = (idx & 127) * 4;
    const float* s0 = Cv + (size_t)row * 512 + m4;
    const float* s1 = s0 + (size_t)32 * 128 * 512;
    float4 a = *(const float4*)s0, bb = *(const float4*)s1;
    _Float16* dst = Vt16 + (size_t)row * 4096 + p + m4;
    dst[0] = (_Float16)(a.x + bb.x); dst[1] = (_Float16)(a.y + bb.y);
    dst[2] = (_Float16)(a.z + bb.z); dst[3] = (_Float16)(a.w + bb.w);
  }
}

// ---------------- flash attention: LDS-staged K/V, 8 waves x 32 q-rows ----------------
// grid = 256 (1/CU): 4 lsplits x 32 heads x 2 m-tiles(256 rows). BL=64.
__global__ __launch_bounds__(512, 2) void attn_part(
    const _Float16* __restrict__ Q16,
    const _Float16* __restrict__ Kc,     // [32][4096][128]
    const _Float16* __restrict__ Vt,     // [32][128][4096]
    float* __restrict__ Opart,           // [4][32][512][128]
    float* __restrict__ Mpart,           // [4][32][512]
    float* __restrict__ Lpart)           // [4][32][512]
{
  __shared__ __align__(16) _Float16 Ks[64 * 128];
  __shared__ __align__(16) _Float16 Vs[128 * 64];
  __shared__ __align__(16) _Float16 Pl[8][32][68];
  const int bid = blockIdx.x;
  const int xcd = bid & 7, s = bid >> 3;
  const int group = xcd * 16 + (s >> 1);
  const int mt = s & 1;
  const int ls = group >> 5, h = group & 31;
  const int m0 = mt * 256;
  const int tid = threadIdx.x, wave = tid >> 6, lane = tid & 63;
  const int g = lane >> 4, c = lane & 15;
  const int mw = m0 + wave * 32;
  const _Float16* Kh  = Kc + (size_t)h * 4096 * 128;
  const _Float16* Vth = Vt + (size_t)h * 128 * 4096;
  f16x8 qf[2][4];
#pragma unroll
  for (int mi = 0; mi < 2; mi++)
#pragma unroll
    for (int kc = 0; kc < 4; kc++)
      qf[mi][kc] = *(const f16x8*)&Q16[(size_t)(h * 512 + mw + mi * 16 + c) * 128 + kc * 32 + g * 8];
  f32x4 o[2][8] = {};
  float mrow[2][4], lrow[2][4];
#pragma unroll
  for (int mi = 0; mi < 2; mi++)
#pragma unroll
    for (int j = 0; j < 4; j++) { mrow[mi][j] = -3e38f; lrow[mi][j] = 0.f; }
  const int klr = lane >> 4, klb = (lane & 15) * 16;
  const int vlr = lane >> 3, vlb = (lane & 7) * 16;

  const int l_begin = ls * 1024;
  for (int l0 = l_begin; l0 < l_begin + 1024; l0 += 64) {
    __syncthreads();
#pragma unroll
    for (int p = 0; p < 2; p++) {
      int chunk = p * 8 + wave;
      int kr = chunk * 4 + klr;
      gload_lds16((const char*)Kh + (size_t)(l0 + kr) * 256 + (klb ^ ((kr & 7) << 4)),
                  (char*)Ks + chunk * 1024);
      int vd = chunk * 8 + vlr;
      gload_lds16((const char*)Vth + (size_t)vd * 8192 + (size_t)l0 * 2 + (vlb ^ ((vd & 7) << 4)),
                  (char*)Vs + chunk * 1024);
    }
    __syncthreads();
    f32x4 sc[2][4] = {};
#pragma unroll
    for (int ni = 0; ni < 4; ni++) {
      int kr = ni * 16 + c;
      f16x8 kf[4];
#pragma unroll
      for (int kc = 0; kc < 4; kc++)
        kf[kc] = *(const f16x8*)((const char*)Ks + kr * 256 + ((kc * 64 + g * 16) ^ ((kr & 7) << 4)));
#pragma unroll
      for (int mi = 0; mi < 2; mi++)
#pragma unroll
        for (int kc = 0; kc < 4; kc++)
          sc[mi][ni] = MFMA16(qf[mi][kc], kf[kc], sc[mi][ni]);
    }
#pragma unroll
    for (int mi = 0; mi < 2; mi++) {
      float scale[4];
#pragma unroll
      for (int j = 0; j < 4; j++) {
        float tm = sc[mi][0][j];
#pragma unroll
        for (int ni = 1; ni < 4; ni++) tm = fmaxf(tm, sc[mi][ni][j]);
        tm = fmaxf(tm, __shfl_xor(tm, 1, 64));
        tm = fmaxf(tm, __shfl_xor(tm, 2, 64));
        tm = fmaxf(tm, __shfl_xor(tm, 4, 64));
        tm = fmaxf(tm, __shfl_xor(tm, 8, 64));
        float mn = fmaxf(mrow[mi][j], tm);
        scale[j] = __expf(mrow[mi][j] - mn);
        mrow[mi][j] = mn;
      }
      float rs[4] = {0.f, 0.f, 0.f, 0.f};
#pragma unroll
      for (int ni = 0; ni < 4; ni++) {
#pragma unroll
        for (int j = 0; j < 4; j++) {
          float pv = __expf(sc[mi][ni][j] - mrow[mi][j]);
          sc[mi][ni][j] = pv;
          rs[j] += pv;
        }
      }
#pragma unroll
      for (int j = 0; j < 4; j++) {
        rs[j] += __shfl_xor(rs[j], 1, 64);
        rs[j] += __shfl_xor(rs[j], 2, 64);
        rs[j] += __shfl_xor(rs[j], 4, 64);
        rs[j] += __shfl_xor(rs[j], 8, 64);
        lrow[mi][j] = lrow[mi][j] * scale[j] + rs[j];
      }
#pragma unroll
      for (int dn = 0; dn < 8; dn++)
#pragma unroll
        for (int j = 0; j < 4; j++) o[mi][dn][j] *= scale[j];
#pragma unroll
      for (int ni = 0; ni < 4; ni++)
#pragma unroll
        for (int j = 0; j < 4; j++)
          Pl[wave][mi * 16 + 4 * g + j][ni * 16 + c] = (_Float16)sc[mi][ni][j];
    }
    f16x8 pa[2][2];
#pragma unroll
    for (int mi = 0; mi < 2; mi++)
#pragma unroll
      for (int kc = 0; kc < 2; kc++)
        pa[mi][kc] = *(const f16x8*)&Pl[wave][mi * 16 + c][kc * 32 + g * 8];
#pragma unroll
    for (int dn = 0; dn < 8; dn++) {
      int vr = dn * 16 + c;
#pragma unroll
      for (int kc = 0; kc < 2; kc++) {
        f16x8 vb = *(const f16x8*)((const char*)Vs + vr * 128 + ((kc * 64 + g * 16) ^ ((vr & 7) << 4)));
#pragma unroll
        for (int mi = 0; mi < 2; mi++)
          o[mi][dn] = MFMA16(pa[mi][kc], vb, o[mi][dn]);
      }
    }
  }
  const size_t pbase = ((size_t)(ls * 32 + h) * 512);
#pragma unroll
  for (int mi = 0; mi < 2; mi++) {
#pragma unroll
    for (int dn = 0; dn < 8; dn++) {
#pragma unroll
      for (int j = 0; j < 4; j++) {
        int m = mw + mi * 16 + 4 * g + j;
        Opart[(pbase + m) * 128 + dn * 16 + c] = o[mi][dn][j];
      }
    }
  }
  if (c == 0) {
#pragma unroll
    for (int mi = 0; mi < 2; mi++)
#pragma unroll
      for (int j = 0; j < 4; j++) {
        int m = mw + mi * 16 + 4 * g + j;
        Mpart[pbase + m] = mrow[mi][j];
        Lpart[pbase + m] = lrow[mi][j];
      }
  }
}

// ---------------- combine 4 split-L partials ----------------
__global__ __launch_bounds__(256) void attn_combine(
    const float* __restrict__ Opart,
    const float* __restrict__ Mpart,
    const float* __restrict__ Lpart,
    float* __restrict__ out)
{
  int idx = blockIdx.x * 256 + threadIdx.x;
  int row = idx >> 5;
  int d4  = idx & 31;
  int h = row >> 9, m = row & 511;
  float Ms[4];
  float mx = -3e38f;
#pragma unroll
  for (int s = 0; s < 4; s++) {
    Ms[s] = Mpart[(size_t)(s * 32 + h) * 512 + m];
    mx = fmaxf(mx, Ms[s]);
  }
  float lsum = 0.f;
  float4 acc = make_float4(0.f, 0.f, 0.f, 0.f);
#pragma unroll
  for (int s = 0; s < 4; s++) {
    float w = __expf(Ms[s] - mx);
    lsum += w * Lpart[(size_t)(s * 32 + h) * 512 + m];
    float4 ov = ((const float4*)(Opart + ((size_t)(s * 32 + h) * 512 + m) * 128))[d4];
    acc.x += w * ov.x; acc.y += w * ov.y; acc.z += w * ov.z; acc.w += w * ov.w;
  }
  float inv = 1.f / lsum;
  float4 r = make_float4(acc.x * inv, acc.y * inv, acc.z * inv, acc.w * inv);
  *(float4*)&out[(size_t)m * 4096 + h * 128 + d4 * 4] = r;
}

extern "C" void kernel_launch(void* const* d_in, const int* in_sizes, int n_in,
                              void* d_out, int out_size, void* d_ws, size_t ws_size,
                              hipStream_t stream) {
  const float* X  = (const float*)d_in[0];
  const float* Wq = (const float*)d_in[1];
  const float* Wk = (const float*)d_in[2];
  const float* Wv = (const float*)d_in[3];
  const float* cK = (const float*)d_in[4];
  const float* cV = (const float*)d_in[5];
  const int*   Pp = (const int*)d_in[6];
  float* out = (float*)d_out;

  char* ws = (char*)d_ws;
  _Float16* X16  = (_Float16*)(ws);                           // 0..4 MB
  float* Opart = (float*)(ws + ((size_t)4  << 20));           // 4..36 MB
  float* Mpart = (float*)(ws + ((size_t)36 << 20));           // 36..37
  float* Lpart = (float*)(ws + ((size_t)37 << 20));           // 37..38
  float* Cqk   = (float*)(ws + ((size_t)40 << 20));           // 40..73.6 MB [2][512][8192] f32
  float* Cv    = (float*)(ws + ((size_t)74 << 20));           // 74..90.8 MB [2][32][128][512] f32
  _Float16* Q16  = (_Float16*)(ws + ((size_t)100 << 20));     // 100..104
  _Float16* K16  = (_Float16*)(ws + ((size_t)104 << 20));     // 104..136 [32][4096][128]
  _Float16* V16t = (_Float16*)(ws + ((size_t)136 << 20));     // 136..168 [32][128][4096]

  const int NTH = 256;
  auto cvtl = [&](const float* s, _Float16* d, size_t n) {
    int n8 = (int)(n / 8);
    int grid = (n8 + NTH - 1) / NTH;
    if (grid > 2048) grid = 2048;
    cvt_f32_f16<<<dim3(grid), dim3(NTH), 0, stream>>>(s, d, n8);
  };
  cvtl(X,  X16, (size_t)512 * 4096);
  cvtl(cK, K16, (size_t)32 * 4096 * 128);
  cvt_transpose_v<<<dim3(4096), dim3(NTH), 0, stream>>>(cV, V16t);

  qkv_gemm<<<dim3(768), dim3(256), 0, stream>>>(X16, Wq, Wk, Wv, Cqk, Cv);
  qkv_reduce<<<dim3(6144), dim3(256), 0, stream>>>(Cqk, Cv, Q16, K16, V16t, Pp);
  attn_part<<<dim3(256), dim3(512), 0, stream>>>(Q16, K16, V16t, Opart, Mpart, Lpart);
  attn_combine<<<dim3(2048), dim3(256), 0, stream>>>(Opart, Mpart, Lpart, out);
}

// Round 9
// 258.543 us; speedup vs baseline: 1.1461x; 1.0337x over previous
//
#include <hip/hip_runtime.h>
#include <hip/hip_fp16.h>

typedef _Float16 f16x8 __attribute__((ext_vector_type(8)));
typedef float    f32x4 __attribute__((ext_vector_type(4)));

#define MFMA16(a,b,c) __builtin_amdgcn_mfma_f32_16x16x32_f16(a,b,c,0,0,0)

__device__ __forceinline__ void gload_lds16(const void* g, void* l) {
  __builtin_amdgcn_global_load_lds(
      (const __attribute__((address_space(1))) void*)g,
      (__attribute__((address_space(3))) void*)l, 16, 0, 0);
}

// ---------------- fp32 -> fp16 conversion ----------------
__global__ void cvt_f32_f16(const float* __restrict__ src,
                            _Float16* __restrict__ dst, int n8) {
  int i = blockIdx.x * blockDim.x + threadIdx.x;
  int stride = gridDim.x * blockDim.x;
  for (; i < n8; i += stride) {
    const float4* s = (const float4*)src + 2 * (size_t)i;
    float4 a = s[0], b = s[1];
    f16x8 o;
    o[0]=(_Float16)a.x; o[1]=(_Float16)a.y; o[2]=(_Float16)a.z; o[3]=(_Float16)a.w;
    o[4]=(_Float16)b.x; o[5]=(_Float16)b.y; o[6]=(_Float16)b.z; o[7]=(_Float16)b.w;
    ((f16x8*)dst)[i] = o;
  }
}

// ---------------- cache_V f32 [32][4096][128] -> V^T f16 [32][128][4096] ----------------
__global__ __launch_bounds__(256) void cvt_transpose_v(const float* __restrict__ src,
                                                       _Float16* __restrict__ dst) {
  __shared__ _Float16 t[64][72];
  const int b = blockIdx.x;        // 32 h x 64 l-tiles x 2 d-tiles
  const int h = b >> 7, rest = b & 127;
  const int lt = rest >> 1, dt = rest & 1;
  const int l0 = lt * 64, d0 = dt * 64;
  const int tid = threadIdx.x;
  const int r = tid >> 4, c4 = (tid & 15) * 4;
#pragma unroll
  for (int i = 0; i < 4; i++) {
    int l = r + i * 16;
    float4 v = *(const float4*)&src[((size_t)h * 4096 + l0 + l) * 128 + d0 + c4];
    t[c4 + 0][l] = (_Float16)v.x;
    t[c4 + 1][l] = (_Float16)v.y;
    t[c4 + 2][l] = (_Float16)v.z;
    t[c4 + 3][l] = (_Float16)v.w;
  }
  __syncthreads();
  const int d = tid >> 2, lc = (tid & 3) * 16;
#pragma unroll
  for (int i = 0; i < 2; i++) {
    f16x8 o = *(const f16x8*)&t[d][lc + i * 8];
    *(f16x8*)&dst[((size_t)h * 128 + d0 + d) * 4096 + l0 + lc + i * 8] = o;
  }
}

// ---------------- fused QKV GEMM: 128x64 tile (R5 structure), split-K=2 ----------------
// Grid 1536 = 8 XCD x (24 nt x 2 ks x 4 mt) -> 6 blocks/CU co-resident.
// Plain 2-barrier loop; A via gload_lds (swizzled global src), B f32 reg-staged + cvt.
// f32 partials: Cqk[ks][512][8192] (Q,K), Cv[ks][32][128][512] (V, d-major).
__global__ __launch_bounds__(256, 6) void qkv_gemm(
    const _Float16* __restrict__ X,
    const float* __restrict__ Wq,
    const float* __restrict__ Wk,
    const float* __restrict__ Wv,
    float* __restrict__ Cqk,            // [2][512][8192]
    float* __restrict__ Cv)             // [2][32][128][512]
{
  __shared__ __align__(16) _Float16 As[128 * 64];   // 16KB, 128B rows, XOR-swizzled
  __shared__ __align__(16) _Float16 Bs[64 * 64];    // 8KB,  128B rows, XOR-swizzled
  const int bid = blockIdx.x;                 // 1536 = 8 xcd * 192
  const int xcd = bid & 7, s = bid >> 3;      // s 0..191
  const int nt = xcd * 24 + (s >> 3);         // 0..191: 24 consecutive n-panels/XCD
  const int ks = (s >> 2) & 1;                // k-split half
  const int mt = s & 3;                       // 4 m-blocks of same (nt,ks) co-XCD
  const int m0 = mt * 128, n0 = nt * 64;
  const int kbase = ks * 2048, kend = kbase + 2048;
  const int tid = threadIdx.x, wave = tid >> 6, lane = tid & 63;
  const int g = lane >> 4, c = lane & 15;
  const int wr = wave >> 1, wc = wave & 1;    // wave tile = 64m x 32n
  const float* Wp = (n0 < 4096) ? Wq : ((n0 < 8192) ? Wk : Wv);
  const int n0l = n0 & 4095;
  // A staging: 16 chunks x 8 rows x 128B; lane -> row ar, byte col acs
  const int ar  = lane >> 3;
  const int acs = (lane & 7) * 16;
  // B staging: 4 threads/row; thread covers 16 consecutive f32
  const int brow = tid >> 2;                  // 0..63
  const int bc32 = (tid & 3) * 16;
  const float* wsrc = Wp + (size_t)(n0l + brow) * 4096 + bc32;
  const int bsw = (brow & 7) << 4;

  float4 b0, b1, b2, b3;                      // 16 f32 in flight
  auto loadB = [&](int k0) {
    const float* ns = wsrc + k0;
    b0 = *(const float4*)(ns);      b1 = *(const float4*)(ns + 4);
    b2 = *(const float4*)(ns + 8);  b3 = *(const float4*)(ns + 12);
  };
  auto writeB = [&]() {
    f16x8 h0, h1;
    h0[0]=(_Float16)b0.x; h0[1]=(_Float16)b0.y; h0[2]=(_Float16)b0.z; h0[3]=(_Float16)b0.w;
    h0[4]=(_Float16)b1.x; h0[5]=(_Float16)b1.y; h0[6]=(_Float16)b1.z; h0[7]=(_Float16)b1.w;
    h1[0]=(_Float16)b2.x; h1[1]=(_Float16)b2.y; h1[2]=(_Float16)b2.z; h1[3]=(_Float16)b2.w;
    h1[4]=(_Float16)b3.x; h1[5]=(_Float16)b3.y; h1[6]=(_Float16)b3.z; h1[7]=(_Float16)b3.w;
    char* rb = (char*)Bs + brow * 128;
    *(f16x8*)(rb + (((tid & 3) * 32)      ^ bsw)) = h0;
    *(f16x8*)(rb + (((tid & 3) * 32 + 16) ^ bsw)) = h1;
  };

  f32x4 acc[4][2] = {};
  loadB(kbase);
  for (int k0 = kbase; k0 < kend; k0 += 64) {
    __syncthreads();                          // waves done reading prev tile
#pragma unroll
    for (int p = 0; p < 4; p++) {
      int chunk = wave * 4 + p;
      int row = chunk * 8 + ar;
      gload_lds16((const char*)(X + (size_t)(m0 + row) * 4096 + k0) + (acs ^ ((row & 7) << 4)),
                  (char*)As + chunk * 1024);
    }
    writeB();
    if (k0 + 64 < kend) loadB(k0 + 64);       // latency covered by MFMA phase
    __syncthreads();                          // staged data visible
    f16x8 af[2][4], bf[2][2];
#pragma unroll
    for (int mi = 0; mi < 4; mi++) {
      int row = wr * 64 + mi * 16 + c;
      int sw = (row & 7) << 4;
#pragma unroll
      for (int kc = 0; kc < 2; kc++)
        af[kc][mi] = *(const f16x8*)((const char*)As + row * 128 + ((kc * 64 + g * 16) ^ sw));
    }
#pragma unroll
    for (int ni = 0; ni < 2; ni++) {
      int row = wc * 32 + ni * 16 + c;
      int sw = (row & 7) << 4;
#pragma unroll
      for (int kc = 0; kc < 2; kc++)
        bf[kc][ni] = *(const f16x8*)((const char*)Bs + row * 128 + ((kc * 64 + g * 16) ^ sw));
    }
#pragma unroll
    for (int kc = 0; kc < 2; kc++)
#pragma unroll
      for (int mi = 0; mi < 4; mi++)
#pragma unroll
        for (int ni = 0; ni < 2; ni++)
          acc[mi][ni] = MFMA16(af[kc][mi], bf[kc][ni], acc[mi][ni]);
  }
  // ---- epilogue: f32 partials ----
  const int wsel = n0 >> 12;
  const int h = (n0 & 4095) >> 7;
  if (wsel < 2) {
    float* Cq = Cqk + (size_t)ks * 512 * 8192;
    const int ncol0 = (n0 & 4095) + (wsel ? 4096 : 0);
#pragma unroll
    for (int mi = 0; mi < 4; mi++)
#pragma unroll
      for (int ni = 0; ni < 2; ni++)
#pragma unroll
        for (int j = 0; j < 4; j++) {
          int m = m0 + wr * 64 + mi * 16 + 4 * g + j;
          int d = wc * 32 + ni * 16 + c;
          Cq[(size_t)m * 8192 + ncol0 + d] = acc[mi][ni][j];
        }
  } else {
    float* Cvp = Cv + (size_t)ks * 32 * 128 * 512;
#pragma unroll
    for (int mi = 0; mi < 4; mi++)
#pragma unroll
      for (int ni = 0; ni < 2; ni++) {
        int mb = m0 + wr * 64 + mi * 16 + 4 * g;
        int d = (n0 & 127) + wc * 32 + ni * 16 + c;
        *(f32x4*)&Cvp[((size_t)(h * 128 + d)) * 512 + mb] = acc[mi][ni];  // 16B contiguous
      }
  }
}

// ---------------- reduce split-K partials -> f16 Q/K/V^T ----------------
// blocks [0,4096): QK part; [4096,6144): V part.
__global__ __launch_bounds__(256) void qkv_reduce(
    const float* __restrict__ Cqk,      // [2][512][8192]
    const float* __restrict__ Cv,       // [2][32][128][512]
    _Float16* __restrict__ Q16,         // [32][512][128]
    _Float16* __restrict__ Kc,          // [32][4096][128]
    _Float16* __restrict__ Vt16,        // [32][128][4096]
    const int* __restrict__ Pp)
{
  const int p = Pp[0];
  const int b = blockIdx.x;
  if (b < 4096) {
    int idx = b * 256 + threadIdx.x;        // [m][8192/4]
    int m = idx >> 11, n4 = (idx & 2047) * 4;
    const float* s0 = Cqk + (size_t)m * 8192 + n4;
    const float* s1 = s0 + (size_t)512 * 8192;
    float4 a = *(const float4*)s0, bb = *(const float4*)s1;
    _Float16 r0 = (_Float16)(a.x + bb.x), r1 = (_Float16)(a.y + bb.y);
    _Float16 r2 = (_Float16)(a.z + bb.z), r3 = (_Float16)(a.w + bb.w);
    _Float16* dst;
    if (n4 < 4096) {
      int h = n4 >> 7, d = n4 & 127;
      dst = Q16 + (size_t)(h * 512 + m) * 128 + d;
    } else {
      int nk = n4 - 4096;
      int h = nk >> 7, d = nk & 127;
      dst = Kc + (size_t)(h * 4096 + p + m) * 128 + d;
    }
    dst[0] = r0; dst[1] = r1; dst[2] = r2; dst[3] = r3;
  } else {
    int idx = (b - 4096) * 256 + threadIdx.x;   // [h*128+d][512/4]
    int row = idx >> 7, m4 = (idx & 127) * 4;
    const float* s0 = Cv + (size_t)row * 512 + m4;
    const float* s1 = s0 + (size_t)32 * 128 * 512;
    float4 a = *(const float4*)s0, bb = *(const float4*)s1;
    _Float16* dst = Vt16 + (size_t)row * 4096 + p + m4;
    dst[0] = (_Float16)(a.x + bb.x); dst[1] = (_Float16)(a.y + bb.y);
    dst[2] = (_Float16)(a.z + bb.z); dst[3] = (_Float16)(a.w + bb.w);
  }
}

// ---------------- flash attention: LDS-staged K/V, 8 waves x 32 q-rows ----------------
// grid = 256 (1/CU): 4 lsplits x 32 heads x 2 m-tiles(256 rows). BL=64.
__global__ __launch_bounds__(512, 2) void attn_part(
    const _Float16* __restrict__ Q16,
    const _Float16* __restrict__ Kc,     // [32][4096][128]
    const _Float16* __restrict__ Vt,     // [32][128][4096]
    float* __restrict__ Opart,           // [4][32][512][128]
    float* __restrict__ Mpart,           // [4][32][512]
    float* __restrict__ Lpart)           // [4][32][512]
{
  __shared__ __align__(16) _Float16 Ks[64 * 128];
  __shared__ __align__(16) _Float16 Vs[128 * 64];
  __shared__ __align__(16) _Float16 Pl[8][32][68];
  const int bid = blockIdx.x;
  const int xcd = bid & 7, s = bid >> 3;
  const int group = xcd * 16 + (s >> 1);
  const int mt = s & 1;
  const int ls = group >> 5, h = group & 31;
  const int m0 = mt * 256;
  const int tid = threadIdx.x, wave = tid >> 6, lane = tid & 63;
  const int g = lane >> 4, c = lane & 15;
  const int mw = m0 + wave * 32;
  const _Float16* Kh  = Kc + (size_t)h * 4096 * 128;
  const _Float16* Vth = Vt + (size_t)h * 128 * 4096;
  f16x8 qf[2][4];
#pragma unroll
  for (int mi = 0; mi < 2; mi++)
#pragma unroll
    for (int kc = 0; kc < 4; kc++)
      qf[mi][kc] = *(const f16x8*)&Q16[(size_t)(h * 512 + mw + mi * 16 + c) * 128 + kc * 32 + g * 8];
  f32x4 o[2][8] = {};
  float mrow[2][4], lrow[2][4];
#pragma unroll
  for (int mi = 0; mi < 2; mi++)
#pragma unroll
    for (int j = 0; j < 4; j++) { mrow[mi][j] = -3e38f; lrow[mi][j] = 0.f; }
  const int klr = lane >> 4, klb = (lane & 15) * 16;
  const int vlr = lane >> 3, vlb = (lane & 7) * 16;

  const int l_begin = ls * 1024;
  for (int l0 = l_begin; l0 < l_begin + 1024; l0 += 64) {
    __syncthreads();
#pragma unroll
    for (int p = 0; p < 2; p++) {
      int chunk = p * 8 + wave;
      int kr = chunk * 4 + klr;
      gload_lds16((const char*)Kh + (size_t)(l0 + kr) * 256 + (klb ^ ((kr & 7) << 4)),
                  (char*)Ks + chunk * 1024);
      int vd = chunk * 8 + vlr;
      gload_lds16((const char*)Vth + (size_t)vd * 8192 + (size_t)l0 * 2 + (vlb ^ ((vd & 7) << 4)),
                  (char*)Vs + chunk * 1024);
    }
    __syncthreads();
    f32x4 sc[2][4] = {};
#pragma unroll
    for (int ni = 0; ni < 4; ni++) {
      int kr = ni * 16 + c;
      f16x8 kf[4];
#pragma unroll
      for (int kc = 0; kc < 4; kc++)
        kf[kc] = *(const f16x8*)((const char*)Ks + kr * 256 + ((kc * 64 + g * 16) ^ ((kr & 7) << 4)));
#pragma unroll
      for (int mi = 0; mi < 2; mi++)
#pragma unroll
        for (int kc = 0; kc < 4; kc++)
          sc[mi][ni] = MFMA16(qf[mi][kc], kf[kc], sc[mi][ni]);
    }
#pragma unroll
    for (int mi = 0; mi < 2; mi++) {
      float scale[4];
#pragma unroll
      for (int j = 0; j < 4; j++) {
        float tm = sc[mi][0][j];
#pragma unroll
        for (int ni = 1; ni < 4; ni++) tm = fmaxf(tm, sc[mi][ni][j]);
        tm = fmaxf(tm, __shfl_xor(tm, 1, 64));
        tm = fmaxf(tm, __shfl_xor(tm, 2, 64));
        tm = fmaxf(tm, __shfl_xor(tm, 4, 64));
        tm = fmaxf(tm, __shfl_xor(tm, 8, 64));
        float mn = fmaxf(mrow[mi][j], tm);
        scale[j] = __expf(mrow[mi][j] - mn);
        mrow[mi][j] = mn;
      }
      float rs[4] = {0.f, 0.f, 0.f, 0.f};
#pragma unroll
      for (int ni = 0; ni < 4; ni++) {
#pragma unroll
        for (int j = 0; j < 4; j++) {
          float pv = __expf(sc[mi][ni][j] - mrow[mi][j]);
          sc[mi][ni][j] = pv;
          rs[j] += pv;
        }
      }
#pragma unroll
      for (int j = 0; j < 4; j++) {
        rs[j] += __shfl_xor(rs[j], 1, 64);
        rs[j] += __shfl_xor(rs[j], 2, 64);
        rs[j] += __shfl_xor(rs[j], 4, 64);
        rs[j] += __shfl_xor(rs[j], 8, 64);
        lrow[mi][j] = lrow[mi][j] * scale[j] + rs[j];
      }
#pragma unroll
      for (int dn = 0; dn < 8; dn++)
#pragma unroll
        for (int j = 0; j < 4; j++) o[mi][dn][j] *= scale[j];
#pragma unroll
      for (int ni = 0; ni < 4; ni++)
#pragma unroll
        for (int j = 0; j < 4; j++)
          Pl[wave][mi * 16 + 4 * g + j][ni * 16 + c] = (_Float16)sc[mi][ni][j];
    }
    f16x8 pa[2][2];
#pragma unroll
    for (int mi = 0; mi < 2; mi++)
#pragma unroll
      for (int kc = 0; kc < 2; kc++)
        pa[mi][kc] = *(const f16x8*)&Pl[wave][mi * 16 + c][kc * 32 + g * 8];
#pragma unroll
    for (int dn = 0; dn < 8; dn++) {
      int vr = dn * 16 + c;
#pragma unroll
      for (int kc = 0; kc < 2; kc++) {
        f16x8 vb = *(const f16x8*)((const char*)Vs + vr * 128 + ((kc * 64 + g * 16) ^ ((vr & 7) << 4)));
#pragma unroll
        for (int mi = 0; mi < 2; mi++)
          o[mi][dn] = MFMA16(pa[mi][kc], vb, o[mi][dn]);
      }
    }
  }
  const size_t pbase = ((size_t)(ls * 32 + h) * 512);
#pragma unroll
  for (int mi = 0; mi < 2; mi++) {
#pragma unroll
    for (int dn = 0; dn < 8; dn++) {
#pragma unroll
      for (int j = 0; j < 4; j++) {
        int m = mw + mi * 16 + 4 * g + j;
        Opart[(pbase + m) * 128 + dn * 16 + c] = o[mi][dn][j];
      }
    }
  }
  if (c == 0) {
#pragma unroll
    for (int mi = 0; mi < 2; mi++)
#pragma unroll
      for (int j = 0; j < 4; j++) {
        int m = mw + mi * 16 + 4 * g + j;
        Mpart[pbase + m] = mrow[mi][j];
        Lpart[pbase + m] = lrow[mi][j];
      }
  }
}

// ---------------- combine 4 split-L partials ----------------
__global__ __launch_bounds__(256) void attn_combine(
    const float* __restrict__ Opart,
    const float* __restrict__ Mpart,
    const float* __restrict__ Lpart,
    float* __restrict__ out)
{
  int idx = blockIdx.x * 256 + threadIdx.x;
  int row = idx >> 5;
  int d4  = idx & 31;
  int h = row >> 9, m = row & 511;
  float Ms[4];
  float mx = -3e38f;
#pragma unroll
  for (int s = 0; s < 4; s++) {
    Ms[s] = Mpart[(size_t)(s * 32 + h) * 512 + m];
    mx = fmaxf(mx, Ms[s]);
  }
  float lsum = 0.f;
  float4 acc = make_float4(0.f, 0.f, 0.f, 0.f);
#pragma unroll
  for (int s = 0; s < 4; s++) {
    float w = __expf(Ms[s] - mx);
    lsum += w * Lpart[(size_t)(s * 32 + h) * 512 + m];
    float4 ov = ((const float4*)(Opart + ((size_t)(s * 32 + h) * 512 + m) * 128))[d4];
    acc.x += w * ov.x; acc.y += w * ov.y; acc.z += w * ov.z; acc.w += w * ov.w;
  }
  float inv = 1.f / lsum;
  float4 r = make_float4(acc.x * inv, acc.y * inv, acc.z * inv, acc.w * inv);
  *(float4*)&out[(size_t)m * 4096 + h * 128 + d4 * 4] = r;
}

extern "C" void kernel_launch(void* const* d_in, const int* in_sizes, int n_in,
                              void* d_out, int out_size, void* d_ws, size_t ws_size,
                              hipStream_t stream) {
  const float* X  = (const float*)d_in[0];
  const float* Wq = (const float*)d_in[1];
  const float* Wk = (const float*)d_in[2];
  const float* Wv = (const float*)d_in[3];
  const float* cK = (const float*)d_in[4];
  const float* cV = (const float*)d_in[5];
  const int*   Pp = (const int*)d_in[6];
  float* out = (float*)d_out;

  char* ws = (char*)d_ws;
  _Float16* X16  = (_Float16*)(ws);                           // 0..4 MB
  float* Opart = (float*)(ws + ((size_t)4  << 20));           // 4..36 MB
  float* Mpart = (float*)(ws + ((size_t)36 << 20));           // 36..37
  float* Lpart = (float*)(ws + ((size_t)37 << 20));           // 37..38
  float* Cqk   = (float*)(ws + ((size_t)40 << 20));           // 40..73.6 MB [2][512][8192] f32
  float* Cv    = (float*)(ws + ((size_t)74 << 20));           // 74..90.8 MB [2][32][128][512] f32
  _Float16* Q16  = (_Float16*)(ws + ((size_t)100 << 20));     // 100..104
  _Float16* K16  = (_Float16*)(ws + ((size_t)104 << 20));     // 104..136 [32][4096][128]
  _Float16* V16t = (_Float16*)(ws + ((size_t)136 << 20));     // 136..168 [32][128][4096]

  const int NTH = 256;
  auto cvtl = [&](const float* s, _Float16* d, size_t n) {
    int n8 = (int)(n / 8);
    int grid = (n8 + NTH - 1) / NTH;
    if (grid > 2048) grid = 2048;
    cvt_f32_f16<<<dim3(grid), dim3(NTH), 0, stream>>>(s, d, n8);
  };
  cvtl(X,  X16, (size_t)512 * 4096);
  cvtl(cK, K16, (size_t)32 * 4096 * 128);
  cvt_transpose_v<<<dim3(4096), dim3(NTH), 0, stream>>>(cV, V16t);

  qkv_gemm<<<dim3(1536), dim3(256), 0, stream>>>(X16, Wq, Wk, Wv, Cqk, Cv);
  qkv_reduce<<<dim3(6144), dim3(256), 0, stream>>>(Cqk, Cv, Q16, K16, V16t, Pp);
  attn_part<<<dim3(256), dim3(512), 0, stream>>>(Q16, K16, V16t, Opart, Mpart, Lpart);
  attn_combine<<<dim3(2048), dim3(256), 0, stream>>>(Opart, Mpart, Lpart, out);
}

// Round 10
// 250.170 us; speedup vs baseline: 1.1845x; 1.0335x over previous
//
#include <hip/hip_runtime.h>
#include <hip/hip_fp16.h>

typedef _Float16 f16x8 __attribute__((ext_vector_type(8)));
typedef float    f32x4 __attribute__((ext_vector_type(4)));

#define MFMA16(a,b,c) __builtin_amdgcn_mfma_f32_16x16x32_f16(a,b,c,0,0,0)

__device__ __forceinline__ void gload_lds16(const void* g, void* l) {
  __builtin_amdgcn_global_load_lds(
      (const __attribute__((address_space(1))) void*)g,
      (__attribute__((address_space(3))) void*)l, 16, 0, 0);
}

// ---------------- fp32 -> fp16 conversion ----------------
__global__ void cvt_f32_f16(const float* __restrict__ src,
                            _Float16* __restrict__ dst, int n8) {
  int i = blockIdx.x * blockDim.x + threadIdx.x;
  int stride = gridDim.x * blockDim.x;
  for (; i < n8; i += stride) {
    const float4* s = (const float4*)src + 2 * (size_t)i;
    float4 a = s[0], b = s[1];
    f16x8 o;
    o[0]=(_Float16)a.x; o[1]=(_Float16)a.y; o[2]=(_Float16)a.z; o[3]=(_Float16)a.w;
    o[4]=(_Float16)b.x; o[5]=(_Float16)b.y; o[6]=(_Float16)b.z; o[7]=(_Float16)b.w;
    ((f16x8*)dst)[i] = o;
  }
}

// ---------------- cache_V f32 [32][4096][128] -> V^T f16 [32][128][4096] ----------------
__global__ __launch_bounds__(256) void cvt_transpose_v(const float* __restrict__ src,
                                                       _Float16* __restrict__ dst) {
  __shared__ _Float16 t[64][72];
  const int b = blockIdx.x;        // 32 h x 64 l-tiles x 2 d-tiles
  const int h = b >> 7, rest = b & 127;
  const int lt = rest >> 1, dt = rest & 1;
  const int l0 = lt * 64, d0 = dt * 64;
  const int tid = threadIdx.x;
  const int r = tid >> 4, c4 = (tid & 15) * 4;
#pragma unroll
  for (int i = 0; i < 4; i++) {
    int l = r + i * 16;
    float4 v = *(const float4*)&src[((size_t)h * 4096 + l0 + l) * 128 + d0 + c4];
    t[c4 + 0][l] = (_Float16)v.x;
    t[c4 + 1][l] = (_Float16)v.y;
    t[c4 + 2][l] = (_Float16)v.z;
    t[c4 + 3][l] = (_Float16)v.w;
  }
  __syncthreads();
  const int d = tid >> 2, lc = (tid & 3) * 16;
#pragma unroll
  for (int i = 0; i < 2; i++) {
    f16x8 o = *(const f16x8*)&t[d][lc + i * 8];
    *(f16x8*)&dst[((size_t)h * 128 + d0 + d) * 4096 + l0 + lc + i * 8] = o;
  }
}

// ---------------- fused QKV GEMM (R5 structure, proven 119 us) ----------------
// C[512,12288] = X16 @ [Wq;Wk;Wv]^T. Tile 128m x 64n, BK=64, 768 blocks (3/CU).
__global__ __launch_bounds__(256) void qkv_gemm(
    const _Float16* __restrict__ X,
    const float* __restrict__ Wq,
    const float* __restrict__ Wk,
    const float* __restrict__ Wv,
    _Float16* __restrict__ Q16,
    _Float16* __restrict__ Kc,
    _Float16* __restrict__ Vt16,
    const int* __restrict__ Pp)
{
  __shared__ __align__(16) _Float16 As[128 * 64];   // 16KB, 128B rows, XOR-swizzled
  __shared__ __align__(16) _Float16 Bs[64 * 64];    // 8KB,  128B rows, XOR-swizzled
  const int bid = blockIdx.x;                 // 768 = 8 xcd * 96
  const int xcd = bid & 7, s = bid >> 3;      // s 0..95
  const int nt = xcd * 24 + (s >> 2);         // 24 consecutive n-panels per XCD
  const int mt = s & 3;                       // 4 m-blocks of same panel co-XCD
  const int m0 = mt * 128, n0 = nt * 64;
  const int tid = threadIdx.x, wave = tid >> 6, lane = tid & 63;
  const int g = lane >> 4, c = lane & 15;
  const int wr = wave >> 1, wc = wave & 1;    // wave = 64m x 32n
  const float* Wp = (n0 < 4096) ? Wq : ((n0 < 8192) ? Wk : Wv);
  const int n0l = n0 & 4095;
  const int ar  = lane >> 3;
  const int acs = (lane & 7) * 16;
  const int brow = tid >> 2;
  const int bc32 = (tid & 3) * 16;
  const float* wsrc = Wp + (size_t)(n0l + brow) * 4096 + bc32;
  const int bsw = (brow & 7) << 4;
  float4 breg[4];
#pragma unroll
  for (int i = 0; i < 4; i++) breg[i] = *(const float4*)(wsrc + i * 4);

  f32x4 acc[4][2] = {};
  for (int k0 = 0; k0 < 4096; k0 += 64) {
    __syncthreads();
#pragma unroll
    for (int p = 0; p < 4; p++) {
      int chunk = wave * 4 + p;
      int row = chunk * 8 + ar;
      gload_lds16((const char*)(X + (size_t)(m0 + row) * 4096 + k0) + (acs ^ ((row & 7) << 4)),
                  (char*)As + chunk * 1024);
    }
    {
      const float* bv = (const float*)breg;
      f16x8 h0, h1;
#pragma unroll
      for (int i = 0; i < 8; i++) { h0[i] = (_Float16)bv[i]; h1[i] = (_Float16)bv[8 + i]; }
      char* rb = (char*)Bs + brow * 128;
      *(f16x8*)(rb + (((tid & 3) * 32)      ^ bsw)) = h0;
      *(f16x8*)(rb + (((tid & 3) * 32 + 16) ^ bsw)) = h1;
      if (k0 + 64 < 4096) {
        const float* ns = wsrc + k0 + 64;
#pragma unroll
        for (int i = 0; i < 4; i++) breg[i] = *(const float4*)(ns + i * 4);
      }
    }
    __syncthreads();
    f16x8 af[2][4], bf[2][2];
#pragma unroll
    for (int mi = 0; mi < 4; mi++) {
      int row = wr * 64 + mi * 16 + c;
      int sw = (row & 7) << 4;
#pragma unroll
      for (int kc = 0; kc < 2; kc++)
        af[kc][mi] = *(const f16x8*)((const char*)As + row * 128 + ((kc * 64 + g * 16) ^ sw));
    }
#pragma unroll
    for (int ni = 0; ni < 2; ni++) {
      int row = wc * 32 + ni * 16 + c;
      int sw = (row & 7) << 4;
#pragma unroll
      for (int kc = 0; kc < 2; kc++)
        bf[kc][ni] = *(const f16x8*)((const char*)Bs + row * 128 + ((kc * 64 + g * 16) ^ sw));
    }
#pragma unroll
    for (int kc = 0; kc < 2; kc++)
#pragma unroll
      for (int mi = 0; mi < 4; mi++)
#pragma unroll
        for (int ni = 0; ni < 2; ni++)
          acc[mi][ni] = MFMA16(af[kc][mi], bf[kc][ni], acc[mi][ni]);
  }
  const int p = Pp[0];
  const int wsel = n0 >> 12;
  const int h = (n0 & 4095) >> 7;
  const int dbase = n0 & 127;                 // 0 or 64
#pragma unroll
  for (int mi = 0; mi < 4; mi++) {
#pragma unroll
    for (int ni = 0; ni < 2; ni++) {
#pragma unroll
      for (int j = 0; j < 4; j++) {
        int m = m0 + wr * 64 + mi * 16 + 4 * g + j;
        int d = dbase + wc * 32 + ni * 16 + c;
        _Float16 hv = (_Float16)acc[mi][ni][j];
        if (wsel == 0)      Q16[(size_t)(h * 512 + m) * 128 + d] = hv;
        else if (wsel == 1) Kc[(size_t)(h * 4096 + p + m) * 128 + d] = hv;
        else                Vt16[((size_t)h * 128 + d) * 4096 + p + m] = hv;
      }
    }
  }
}

// ---------------- flash attention: split-L=8, 2 blocks/CU ----------------
// grid = 512: xcd owns one ls slice; per block 256 q-rows x 512 cache pos, BL=64.
__global__ __launch_bounds__(512, 2) void attn_part(
    const _Float16* __restrict__ Q16,
    const _Float16* __restrict__ Kc,     // [32][4096][128]
    const _Float16* __restrict__ Vt,     // [32][128][4096]
    float* __restrict__ Opart,           // [8][32][512][128]
    float* __restrict__ Mpart,           // [8][32][512]
    float* __restrict__ Lpart)           // [8][32][512]
{
  __shared__ __align__(16) _Float16 Ks[64 * 128];
  __shared__ __align__(16) _Float16 Vs[128 * 64];
  __shared__ __align__(16) _Float16 Pl[8][32][68];
  const int bid = blockIdx.x;
  const int xcd = bid & 7, s = bid >> 3;              // s 0..63
  const int ls = xcd;                                 // each XCD owns one ls slice
  const int h = s >> 1;
  const int mt = s & 1;
  const int m0 = mt * 256;
  const int tid = threadIdx.x, wave = tid >> 6, lane = tid & 63;
  const int g = lane >> 4, c = lane & 15;
  const int mw = m0 + wave * 32;
  const _Float16* Kh  = Kc + (size_t)h * 4096 * 128;
  const _Float16* Vth = Vt + (size_t)h * 128 * 4096;
  f16x8 qf[2][4];
#pragma unroll
  for (int mi = 0; mi < 2; mi++)
#pragma unroll
    for (int kc = 0; kc < 4; kc++)
      qf[mi][kc] = *(const f16x8*)&Q16[(size_t)(h * 512 + mw + mi * 16 + c) * 128 + kc * 32 + g * 8];
  f32x4 o[2][8] = {};
  float mrow[2][4], lrow[2][4];
#pragma unroll
  for (int mi = 0; mi < 2; mi++)
#pragma unroll
    for (int j = 0; j < 4; j++) { mrow[mi][j] = -3e38f; lrow[mi][j] = 0.f; }
  const int klr = lane >> 4, klb = (lane & 15) * 16;
  const int vlr = lane >> 3, vlb = (lane & 7) * 16;

  const int l_begin = ls * 512;
  for (int l0 = l_begin; l0 < l_begin + 512; l0 += 64) {
    __syncthreads();
#pragma unroll
    for (int p = 0; p < 2; p++) {
      int chunk = p * 8 + wave;
      int kr = chunk * 4 + klr;
      gload_lds16((const char*)Kh + (size_t)(l0 + kr) * 256 + (klb ^ ((kr & 7) << 4)),
                  (char*)Ks + chunk * 1024);
      int vd = chunk * 8 + vlr;
      gload_lds16((const char*)Vth + (size_t)vd * 8192 + (size_t)l0 * 2 + (vlb ^ ((vd & 7) << 4)),
                  (char*)Vs + chunk * 1024);
    }
    __syncthreads();
    f32x4 sc[2][4] = {};
#pragma unroll
    for (int ni = 0; ni < 4; ni++) {
      int kr = ni * 16 + c;
      f16x8 kf[4];
#pragma unroll
      for (int kc = 0; kc < 4; kc++)
        kf[kc] = *(const f16x8*)((const char*)Ks + kr * 256 + ((kc * 64 + g * 16) ^ ((kr & 7) << 4)));
#pragma unroll
      for (int mi = 0; mi < 2; mi++)
#pragma unroll
        for (int kc = 0; kc < 4; kc++)
          sc[mi][ni] = MFMA16(qf[mi][kc], kf[kc], sc[mi][ni]);
    }
#pragma unroll
    for (int mi = 0; mi < 2; mi++) {
      float scale[4];
#pragma unroll
      for (int j = 0; j < 4; j++) {
        float tm = sc[mi][0][j];
#pragma unroll
        for (int ni = 1; ni < 4; ni++) tm = fmaxf(tm, sc[mi][ni][j]);
        tm = fmaxf(tm, __shfl_xor(tm, 1, 64));
        tm = fmaxf(tm, __shfl_xor(tm, 2, 64));
        tm = fmaxf(tm, __shfl_xor(tm, 4, 64));
        tm = fmaxf(tm, __shfl_xor(tm, 8, 64));
        float mn = fmaxf(mrow[mi][j], tm);
        scale[j] = __expf(mrow[mi][j] - mn);
        mrow[mi][j] = mn;
      }
      float rs[4] = {0.f, 0.f, 0.f, 0.f};
#pragma unroll
      for (int ni = 0; ni < 4; ni++) {
#pragma unroll
        for (int j = 0; j < 4; j++) {
          float pv = __expf(sc[mi][ni][j] - mrow[mi][j]);
          sc[mi][ni][j] = pv;
          rs[j] += pv;
        }
      }
#pragma unroll
      for (int j = 0; j < 4; j++) {
        rs[j] += __shfl_xor(rs[j], 1, 64);
        rs[j] += __shfl_xor(rs[j], 2, 64);
        rs[j] += __shfl_xor(rs[j], 4, 64);
        rs[j] += __shfl_xor(rs[j], 8, 64);
        lrow[mi][j] = lrow[mi][j] * scale[j] + rs[j];
      }
#pragma unroll
      for (int dn = 0; dn < 8; dn++)
#pragma unroll
        for (int j = 0; j < 4; j++) o[mi][dn][j] *= scale[j];
#pragma unroll
      for (int ni = 0; ni < 4; ni++)
#pragma unroll
        for (int j = 0; j < 4; j++)
          Pl[wave][mi * 16 + 4 * g + j][ni * 16 + c] = (_Float16)sc[mi][ni][j];
    }
    f16x8 pa[2][2];
#pragma unroll
    for (int mi = 0; mi < 2; mi++)
#pragma unroll
      for (int kc = 0; kc < 2; kc++)
        pa[mi][kc] = *(const f16x8*)&Pl[wave][mi * 16 + c][kc * 32 + g * 8];
#pragma unroll
    for (int dn = 0; dn < 8; dn++) {
      int vr = dn * 16 + c;
#pragma unroll
      for (int kc = 0; kc < 2; kc++) {
        f16x8 vb = *(const f16x8*)((const char*)Vs + vr * 128 + ((kc * 64 + g * 16) ^ ((vr & 7) << 4)));
#pragma unroll
        for (int mi = 0; mi < 2; mi++)
          o[mi][dn] = MFMA16(pa[mi][kc], vb, o[mi][dn]);
      }
    }
  }
  const size_t pbase = ((size_t)(ls * 32 + h) * 512);
#pragma unroll
  for (int mi = 0; mi < 2; mi++) {
#pragma unroll
    for (int dn = 0; dn < 8; dn++) {
#pragma unroll
      for (int j = 0; j < 4; j++) {
        int m = mw + mi * 16 + 4 * g + j;
        Opart[(pbase + m) * 128 + dn * 16 + c] = o[mi][dn][j];
      }
    }
  }
  if (c == 0) {
#pragma unroll
    for (int mi = 0; mi < 2; mi++)
#pragma unroll
      for (int j = 0; j < 4; j++) {
        int m = mw + mi * 16 + 4 * g + j;
        Mpart[pbase + m] = mrow[mi][j];
        Lpart[pbase + m] = lrow[mi][j];
      }
  }
}

// ---------------- combine 8 split-L partials ----------------
__global__ __launch_bounds__(256) void attn_combine(
    const float* __restrict__ Opart,
    const float* __restrict__ Mpart,
    const float* __restrict__ Lpart,
    float* __restrict__ out)
{
  int idx = blockIdx.x * 256 + threadIdx.x;
  int row = idx >> 5;
  int d4  = idx & 31;
  int h = row >> 9, m = row & 511;
  float Ms[8];
  float mx = -3e38f;
#pragma unroll
  for (int s = 0; s < 8; s++) {
    Ms[s] = Mpart[(size_t)(s * 32 + h) * 512 + m];
    mx = fmaxf(mx, Ms[s]);
  }
  float lsum = 0.f;
  float4 acc = make_float4(0.f, 0.f, 0.f, 0.f);
#pragma unroll
  for (int s = 0; s < 8; s++) {
    float w = __expf(Ms[s] - mx);
    lsum += w * Lpart[(size_t)(s * 32 + h) * 512 + m];
    float4 ov = ((const float4*)(Opart + ((size_t)(s * 32 + h) * 512 + m) * 128))[d4];
    acc.x += w * ov.x; acc.y += w * ov.y; acc.z += w * ov.z; acc.w += w * ov.w;
  }
  float inv = 1.f / lsum;
  float4 r = make_float4(acc.x * inv, acc.y * inv, acc.z * inv, acc.w * inv);
  *(float4*)&out[(size_t)m * 4096 + h * 128 + d4 * 4] = r;
}

extern "C" void kernel_launch(void* const* d_in, const int* in_sizes, int n_in,
                              void* d_out, int out_size, void* d_ws, size_t ws_size,
                              hipStream_t stream) {
  const float* X  = (const float*)d_in[0];
  const float* Wq = (const float*)d_in[1];
  const float* Wk = (const float*)d_in[2];
  const float* Wv = (const float*)d_in[3];
  const float* cK = (const float*)d_in[4];
  const float* cV = (const float*)d_in[5];
  const int*   Pp = (const int*)d_in[6];
  float* out = (float*)d_out;

  char* ws = (char*)d_ws;
  _Float16* X16  = (_Float16*)(ws);                           // 0..4 MB
  float* Opart = (float*)(ws + ((size_t)4  << 20));           // 4..68 MB [8][32][512][128] f32
  float* Mpart = (float*)(ws + ((size_t)68 << 20));           // 68..68.5
  float* Lpart = (float*)(ws + ((size_t)69 << 20));           // 69..69.5
  _Float16* Q16  = (_Float16*)(ws + ((size_t)100 << 20));     // 100..104
  _Float16* K16  = (_Float16*)(ws + ((size_t)104 << 20));     // 104..136 [32][4096][128]
  _Float16* V16t = (_Float16*)(ws + ((size_t)136 << 20));     // 136..168 [32][128][4096]

  const int NTH = 256;
  auto cvtl = [&](const float* s, _Float16* d, size_t n) {
    int n8 = (int)(n / 8);
    int grid = (n8 + NTH - 1) / NTH;
    if (grid > 2048) grid = 2048;
    cvt_f32_f16<<<dim3(grid), dim3(NTH), 0, stream>>>(s, d, n8);
  };
  cvtl(X,  X16, (size_t)512 * 4096);
  cvtl(cK, K16, (size_t)32 * 4096 * 128);
  cvt_transpose_v<<<dim3(4096), dim3(NTH), 0, stream>>>(cV, V16t);

  qkv_gemm<<<dim3(768), dim3(256), 0, stream>>>(X16, Wq, Wk, Wv, Q16, K16, V16t, Pp);
  attn_part<<<dim3(512), dim3(512), 0, stream>>>(Q16, K16, V16t, Opart, Mpart, Lpart);
  attn_combine<<<dim3(2048), dim3(256), 0, stream>>>(Opart, Mpart, Lpart, out);
}

// Round 11
// 224.340 us; speedup vs baseline: 1.3208x; 1.1151x over previous
//
#include <hip/hip_runtime.h>
#include <hip/hip_fp16.h>

typedef _Float16 f16x8 __attribute__((ext_vector_type(8)));
typedef float    f32x4 __attribute__((ext_vector_type(4)));

#define MFMA16(a,b,c) __builtin_amdgcn_mfma_f32_16x16x32_f16(a,b,c,0,0,0)

__device__ __forceinline__ void gload_lds16(const void* g, void* l) {
  __builtin_amdgcn_global_load_lds(
      (const __attribute__((address_space(1))) void*)g,
      (__attribute__((address_space(3))) void*)l, 16, 0, 0);
}

// ---------------- fp32 -> fp16 conversion (X only) ----------------
__global__ void cvt_f32_f16(const float* __restrict__ src,
                            _Float16* __restrict__ dst, int n8) {
  int i = blockIdx.x * blockDim.x + threadIdx.x;
  int stride = gridDim.x * blockDim.x;
  for (; i < n8; i += stride) {
    const float4* s = (const float4*)src + 2 * (size_t)i;
    float4 a = s[0], b = s[1];
    f16x8 o;
    o[0]=(_Float16)a.x; o[1]=(_Float16)a.y; o[2]=(_Float16)a.z; o[3]=(_Float16)a.w;
    o[4]=(_Float16)b.x; o[5]=(_Float16)b.y; o[6]=(_Float16)b.z; o[7]=(_Float16)b.w;
    ((f16x8*)dst)[i] = o;
  }
}

// ---------------- fused: QKV GEMM (768 blocks) + K/V cache cvt (2560 blocks) ----------------
// gemm: R5 structure (proven 119us): 128m x 64n, BK=64, 2-barrier loop, 3/CU.
// cvt blocks fill the gemm's latency bubbles (gemm: HBM 13%, 12/32 wave slots).
// Race-free: cvt skips l in [P,P+512) -- exactly the rows/cols gemm writes.
__global__ __launch_bounds__(256) void qkv_gemm_fused(
    const _Float16* __restrict__ X,
    const float* __restrict__ Wq,
    const float* __restrict__ Wk,
    const float* __restrict__ Wv,
    const float* __restrict__ cK,       // [32][4096][128] f32
    const float* __restrict__ cV,       // [32][4096][128] f32
    _Float16* __restrict__ Q16,
    _Float16* __restrict__ Kc,          // [32][4096][128] f16
    _Float16* __restrict__ Vt16,        // [32][128][4096] f16
    const int* __restrict__ Pp)
{
  __shared__ __align__(16) _Float16 As[128 * 64];   // 16KB (also reused by V-cvt staging)
  __shared__ __align__(16) _Float16 Bs[64 * 64];    // 8KB
  const int bid = blockIdx.x;
  const int tid = threadIdx.x;

  if (bid < 768) {
    // ================= GEMM path (R5, unchanged) =================
    const int xcd = bid & 7, s = bid >> 3;
    const int nt = xcd * 24 + (s >> 2);
    const int mt = s & 3;
    const int m0 = mt * 128, n0 = nt * 64;
    const int wave = tid >> 6, lane = tid & 63;
    const int g = lane >> 4, c = lane & 15;
    const int wr = wave >> 1, wc = wave & 1;
    const float* Wp = (n0 < 4096) ? Wq : ((n0 < 8192) ? Wk : Wv);
    const int n0l = n0 & 4095;
    const int ar  = lane >> 3;
    const int acs = (lane & 7) * 16;
    const int brow = tid >> 2;
    const int bc32 = (tid & 3) * 16;
    const float* wsrc = Wp + (size_t)(n0l + brow) * 4096 + bc32;
    const int bsw = (brow & 7) << 4;
    float4 breg[4];
#pragma unroll
    for (int i = 0; i < 4; i++) breg[i] = *(const float4*)(wsrc + i * 4);

    f32x4 acc[4][2] = {};
    for (int k0 = 0; k0 < 4096; k0 += 64) {
      __syncthreads();
#pragma unroll
      for (int p = 0; p < 4; p++) {
        int chunk = wave * 4 + p;
        int row = chunk * 8 + ar;
        gload_lds16((const char*)(X + (size_t)(m0 + row) * 4096 + k0) + (acs ^ ((row & 7) << 4)),
                    (char*)As + chunk * 1024);
      }
      {
        const float* bv = (const float*)breg;
        f16x8 h0, h1;
#pragma unroll
        for (int i = 0; i < 8; i++) { h0[i] = (_Float16)bv[i]; h1[i] = (_Float16)bv[8 + i]; }
        char* rb = (char*)Bs + brow * 128;
        *(f16x8*)(rb + (((tid & 3) * 32)      ^ bsw)) = h0;
        *(f16x8*)(rb + (((tid & 3) * 32 + 16) ^ bsw)) = h1;
        if (k0 + 64 < 4096) {
          const float* ns = wsrc + k0 + 64;
#pragma unroll
          for (int i = 0; i < 4; i++) breg[i] = *(const float4*)(ns + i * 4);
        }
      }
      __syncthreads();
      f16x8 af[2][4], bf[2][2];
#pragma unroll
      for (int mi = 0; mi < 4; mi++) {
        int row = wr * 64 + mi * 16 + c;
        int sw = (row & 7) << 4;
#pragma unroll
        for (int kc = 0; kc < 2; kc++)
          af[kc][mi] = *(const f16x8*)((const char*)As + row * 128 + ((kc * 64 + g * 16) ^ sw));
      }
#pragma unroll
      for (int ni = 0; ni < 2; ni++) {
        int row = wc * 32 + ni * 16 + c;
        int sw = (row & 7) << 4;
#pragma unroll
        for (int kc = 0; kc < 2; kc++)
          bf[kc][ni] = *(const f16x8*)((const char*)Bs + row * 128 + ((kc * 64 + g * 16) ^ sw));
      }
#pragma unroll
      for (int kc = 0; kc < 2; kc++)
#pragma unroll
        for (int mi = 0; mi < 4; mi++)
#pragma unroll
          for (int ni = 0; ni < 2; ni++)
            acc[mi][ni] = MFMA16(af[kc][mi], bf[kc][ni], acc[mi][ni]);
    }
    const int p = Pp[0];
    const int wsel = n0 >> 12;
    const int h = (n0 & 4095) >> 7;
    const int dbase = n0 & 127;
#pragma unroll
    for (int mi = 0; mi < 4; mi++) {
#pragma unroll
      for (int ni = 0; ni < 2; ni++) {
#pragma unroll
        for (int j = 0; j < 4; j++) {
          int m = m0 + wr * 64 + mi * 16 + 4 * g + j;
          int d = dbase + wc * 32 + ni * 16 + c;
          _Float16 hv = (_Float16)acc[mi][ni][j];
          if (wsel == 0)      Q16[(size_t)(h * 512 + m) * 128 + d] = hv;
          else if (wsel == 1) Kc[(size_t)(h * 4096 + p + m) * 128 + d] = hv;
          else                Vt16[((size_t)h * 128 + d) * 4096 + p + m] = hv;
        }
      }
    }
    return;
  }

  // ================= cvt paths =================
  const int p = Pp[0];
  const int cb = bid - 768;
  if (cb < 512) {
    // ---- cache_K f32 -> K16 f16 (same layout), skip rows [P,P+512) ----
    const int total = 32 * 4096 * 16;          // f16x8 chunks (16 per 128-d row)
    const int stride = 512 * 256;
    for (int i = cb * 256 + tid; i < total; i += stride) {
      int l = (i >> 4) & 4095;
      if ((unsigned)(l - p) < 512u) continue;  // gemm writes these rows
      const float4* s = (const float4*)cK + 2 * (size_t)i;
      float4 a = s[0], b = s[1];
      f16x8 o;
      o[0]=(_Float16)a.x; o[1]=(_Float16)a.y; o[2]=(_Float16)a.z; o[3]=(_Float16)a.w;
      o[4]=(_Float16)b.x; o[5]=(_Float16)b.y; o[6]=(_Float16)b.z; o[7]=(_Float16)b.w;
      ((f16x8*)Kc)[i] = o;
    }
  } else {
    // ---- cache_V f32 [32][4096][128] -> V^T f16 [32][128][4096], skip cols [P,P+512) ----
    _Float16 (*t)[72] = (_Float16 (*)[72])As;  // 64x72 f16 = 9.2KB, fits in As
    const int r = tid >> 4, c4 = (tid & 15) * 4;
    const int d = tid >> 2, lc = (tid & 3) * 16;
#pragma unroll
    for (int rep = 0; rep < 2; rep++) {
      int b = (cb - 512) * 2 + rep;            // 0..4095: 32 h x 64 l-tiles x 2 d-tiles
      int h = b >> 7, rest = b & 127;
      int lt = rest >> 1, dt = rest & 1;
      int l0 = lt * 64, d0 = dt * 64;
      __syncthreads();                         // prev rep's reads done
#pragma unroll
      for (int i = 0; i < 4; i++) {
        int l = r + i * 16;
        float4 v = *(const float4*)&cV[((size_t)h * 4096 + l0 + l) * 128 + d0 + c4];
        t[c4 + 0][l] = (_Float16)v.x;
        t[c4 + 1][l] = (_Float16)v.y;
        t[c4 + 2][l] = (_Float16)v.z;
        t[c4 + 3][l] = (_Float16)v.w;
      }
      __syncthreads();
#pragma unroll
      for (int i = 0; i < 2; i++) {
        int l = l0 + lc + i * 8;               // chunk of 8 l; P is 8-aligned
        if ((unsigned)(l - p) < 512u) continue;  // gemm writes these cols
        f16x8 o = *(const f16x8*)&t[d][lc + i * 8];
        *(f16x8*)&Vt16[((size_t)h * 128 + d0 + d) * 4096 + l] = o;
      }
    }
  }
}

// ---------------- flash attention: split-L=4, 128 q-rows/block, 2 blocks/CU ----------------
// grid = 512 = 8 XCD x (4 groups x 4 mt): the 4 mt-blocks of one (ls,h) share an XCD L2.
// 8 waves x 16 q-rows; BL=64; K/V^T staged via swizzled-source global_load_lds.
__global__ __launch_bounds__(512, 2) void attn_part(
    const _Float16* __restrict__ Q16,
    const _Float16* __restrict__ Kc,     // [32][4096][128]
    const _Float16* __restrict__ Vt,     // [32][128][4096]
    float* __restrict__ Opart,           // [4][32][512][128]
    float* __restrict__ Mpart,           // [4][32][512]
    float* __restrict__ Lpart)           // [4][32][512]
{
  __shared__ __align__(16) _Float16 Ks[64 * 128];     // 16KB
  __shared__ __align__(16) _Float16 Vs[128 * 64];     // 16KB
  __shared__ __align__(16) _Float16 Pl[8][16][68];    // 17KB -> ~49KB total
  const int bid = blockIdx.x;
  const int xcd = bid & 7, s = bid >> 3;              // s 0..63
  const int group = xcd * 16 + (s >> 2);              // 0..127 = ls*32+h
  const int mt = s & 3;
  const int ls = group >> 5, h = group & 31;
  const int m0 = mt * 128;
  const int tid = threadIdx.x, wave = tid >> 6, lane = tid & 63;
  const int g = lane >> 4, c = lane & 15;
  const int mw = m0 + wave * 16;
  const _Float16* Kh  = Kc + (size_t)h * 4096 * 128;
  const _Float16* Vth = Vt + (size_t)h * 128 * 4096;
  f16x8 qf[4];
#pragma unroll
  for (int kc = 0; kc < 4; kc++)
    qf[kc] = *(const f16x8*)&Q16[(size_t)(h * 512 + mw + c) * 128 + kc * 32 + g * 8];
  f32x4 o[8] = {};
  float mrow[4] = {-3e38f, -3e38f, -3e38f, -3e38f};
  float lrow[4] = {0.f, 0.f, 0.f, 0.f};
  const int klr = lane >> 4, klb = (lane & 15) * 16;
  const int vlr = lane >> 3, vlb = (lane & 7) * 16;

  const int l_begin = ls * 1024;
  for (int l0 = l_begin; l0 < l_begin + 1024; l0 += 64) {
    __syncthreads();
#pragma unroll
    for (int p = 0; p < 2; p++) {
      int chunk = p * 8 + wave;
      int kr = chunk * 4 + klr;
      gload_lds16((const char*)Kh + (size_t)(l0 + kr) * 256 + (klb ^ ((kr & 7) << 4)),
                  (char*)Ks + chunk * 1024);
      int vd = chunk * 8 + vlr;
      gload_lds16((const char*)Vth + (size_t)vd * 8192 + (size_t)l0 * 2 + (vlb ^ ((vd & 7) << 4)),
                  (char*)Vs + chunk * 1024);
    }
    __syncthreads();
    // ---- QK^T ----
    f32x4 sc[4] = {};
#pragma unroll
    for (int ni = 0; ni < 4; ni++) {
      int kr = ni * 16 + c;
      f16x8 kf[4];
#pragma unroll
      for (int kc = 0; kc < 4; kc++)
        kf[kc] = *(const f16x8*)((const char*)Ks + kr * 256 + ((kc * 64 + g * 16) ^ ((kr & 7) << 4)));
#pragma unroll
      for (int kc = 0; kc < 4; kc++)
        sc[ni] = MFMA16(qf[kc], kf[kc], sc[ni]);
    }
    // ---- online softmax ----
    float scale[4];
#pragma unroll
    for (int j = 0; j < 4; j++) {
      float tm = sc[0][j];
#pragma unroll
      for (int ni = 1; ni < 4; ni++) tm = fmaxf(tm, sc[ni][j]);
      tm = fmaxf(tm, __shfl_xor(tm, 1, 64));
      tm = fmaxf(tm, __shfl_xor(tm, 2, 64));
      tm = fmaxf(tm, __shfl_xor(tm, 4, 64));
      tm = fmaxf(tm, __shfl_xor(tm, 8, 64));
      float mn = fmaxf(mrow[j], tm);
      scale[j] = __expf(mrow[j] - mn);
      mrow[j] = mn;
    }
    float rs[4] = {0.f, 0.f, 0.f, 0.f};
#pragma unroll
    for (int ni = 0; ni < 4; ni++) {
#pragma unroll
      for (int j = 0; j < 4; j++) {
        float pv = __expf(sc[ni][j] - mrow[j]);
        sc[ni][j] = pv;
        rs[j] += pv;
      }
    }
#pragma unroll
    for (int j = 0; j < 4; j++) {
      rs[j] += __shfl_xor(rs[j], 1, 64);
      rs[j] += __shfl_xor(rs[j], 2, 64);
      rs[j] += __shfl_xor(rs[j], 4, 64);
      rs[j] += __shfl_xor(rs[j], 8, 64);
      lrow[j] = lrow[j] * scale[j] + rs[j];
    }
#pragma unroll
    for (int dn = 0; dn < 8; dn++)
#pragma unroll
      for (int j = 0; j < 4; j++) o[dn][j] *= scale[j];
    // ---- P -> wave-private LDS ----
#pragma unroll
    for (int ni = 0; ni < 4; ni++)
#pragma unroll
      for (int j = 0; j < 4; j++)
        Pl[wave][4 * g + j][ni * 16 + c] = (_Float16)sc[ni][j];
    f16x8 pa[2];
#pragma unroll
    for (int kc = 0; kc < 2; kc++)
      pa[kc] = *(const f16x8*)&Pl[wave][c][kc * 32 + g * 8];
    // ---- PV ----
#pragma unroll
    for (int dn = 0; dn < 8; dn++) {
      int vr = dn * 16 + c;
#pragma unroll
      for (int kc = 0; kc < 2; kc++) {
        f16x8 vb = *(const f16x8*)((const char*)Vs + vr * 128 + ((kc * 64 + g * 16) ^ ((vr & 7) << 4)));
        o[dn] = MFMA16(pa[kc], vb, o[dn]);
      }
    }
  }
  // ---- epilogue ----
  const size_t pbase = ((size_t)(ls * 32 + h) * 512);
#pragma unroll
  for (int dn = 0; dn < 8; dn++) {
#pragma unroll
    for (int j = 0; j < 4; j++) {
      int m = mw + 4 * g + j;
      Opart[(pbase + m) * 128 + dn * 16 + c] = o[dn][j];
    }
  }
  if (c == 0) {
#pragma unroll
    for (int j = 0; j < 4; j++) {
      int m = mw + 4 * g + j;
      Mpart[pbase + m] = mrow[j];
      Lpart[pbase + m] = lrow[j];
    }
  }
}

// ---------------- combine 4 split-L partials ----------------
__global__ __launch_bounds__(256) void attn_combine(
    const float* __restrict__ Opart,
    const float* __restrict__ Mpart,
    const float* __restrict__ Lpart,
    float* __restrict__ out)
{
  int idx = blockIdx.x * 256 + threadIdx.x;
  int row = idx >> 5;
  int d4  = idx & 31;
  int h = row >> 9, m = row & 511;
  float Ms[4];
  float mx = -3e38f;
#pragma unroll
  for (int s = 0; s < 4; s++) {
    Ms[s] = Mpart[(size_t)(s * 32 + h) * 512 + m];
    mx = fmaxf(mx, Ms[s]);
  }
  float lsum = 0.f;
  float4 acc = make_float4(0.f, 0.f, 0.f, 0.f);
#pragma unroll
  for (int s = 0; s < 4; s++) {
    float w = __expf(Ms[s] - mx);
    lsum += w * Lpart[(size_t)(s * 32 + h) * 512 + m];
    float4 ov = ((const float4*)(Opart + ((size_t)(s * 32 + h) * 512 + m) * 128))[d4];
    acc.x += w * ov.x; acc.y += w * ov.y; acc.z += w * ov.z; acc.w += w * ov.w;
  }
  float inv = 1.f / lsum;
  float4 r = make_float4(acc.x * inv, acc.y * inv, acc.z * inv, acc.w * inv);
  *(float4*)&out[(size_t)m * 4096 + h * 128 + d4 * 4] = r;
}

extern "C" void kernel_launch(void* const* d_in, const int* in_sizes, int n_in,
                              void* d_out, int out_size, void* d_ws, size_t ws_size,
                              hipStream_t stream) {
  const float* X  = (const float*)d_in[0];
  const float* Wq = (const float*)d_in[1];
  const float* Wk = (const float*)d_in[2];
  const float* Wv = (const float*)d_in[3];
  const float* cK = (const float*)d_in[4];
  const float* cV = (const float*)d_in[5];
  const int*   Pp = (const int*)d_in[6];
  float* out = (float*)d_out;

  char* ws = (char*)d_ws;
  _Float16* X16  = (_Float16*)(ws);                           // 0..4 MB
  float* Opart = (float*)(ws + ((size_t)4  << 20));           // 4..36 MB [4][32][512][128] f32
  float* Mpart = (float*)(ws + ((size_t)36 << 20));           // 36..37
  float* Lpart = (float*)(ws + ((size_t)37 << 20));           // 37..38
  _Float16* Q16  = (_Float16*)(ws + ((size_t)100 << 20));     // 100..104
  _Float16* K16  = (_Float16*)(ws + ((size_t)104 << 20));     // 104..136 [32][4096][128]
  _Float16* V16t = (_Float16*)(ws + ((size_t)136 << 20));     // 136..168 [32][128][4096]

  // X cvt (gemm input) — must precede the fused kernel
  cvt_f32_f16<<<dim3(1024), dim3(256), 0, stream>>>(X, X16, 512 * 4096 / 8);

  // fused: 768 gemm blocks + 512 K-cvt blocks + 2048 V-transpose-cvt blocks
  qkv_gemm_fused<<<dim3(768 + 512 + 2048), dim3(256), 0, stream>>>(
      X16, Wq, Wk, Wv, cK, cV, Q16, K16, V16t, Pp);

  attn_part<<<dim3(512), dim3(512), 0, stream>>>(Q16, K16, V16t, Opart, Mpart, Lpart);
  attn_combine<<<dim3(2048), dim3(256), 0, stream>>>(Opart, Mpart, Lpart, out);
}